// Round 1
// baseline (3993.737 us; speedup 1.0000x reference)
//
#include <hip/hip_runtime.h>
#include <math.h>

typedef unsigned short u16;
typedef unsigned int u32;

#define D_ 2048
#define S_ 2048
#define DH_ 128
#define NH_ 16
#define F_ 5504
#define MTOK 4096

typedef __bf16 bf16x8 __attribute__((ext_vector_type(8)));
typedef float f32x4 __attribute__((ext_vector_type(4)));

__device__ __forceinline__ float bf2f(u32 u) {
  union { u32 i; float f; } x; x.i = u << 16; return x.f;
}
__device__ __forceinline__ u16 f2bf(float f) {
  u32 x = __float_as_uint(f);
  return (u16)((x + 0x7fffu + ((x >> 16) & 1u)) >> 16);
}

// ---------------- fp32 -> bf16 elementwise convert (weights) ----------
__global__ __launch_bounds__(256)
void k_f2bf(const float* __restrict__ src, u16* __restrict__ dst) {
  const size_t i = ((size_t)blockIdx.x * 256 + threadIdx.x) * 8;
  float4 a = *(const float4*)(src + i);
  float4 b = *(const float4*)(src + i + 4);
  uint4 p;
  p.x = f2bf(a.x) | ((u32)f2bf(a.y) << 16);
  p.y = f2bf(a.z) | ((u32)f2bf(a.w) << 16);
  p.z = f2bf(b.x) | ((u32)f2bf(b.y) << 16);
  p.w = f2bf(b.z) | ((u32)f2bf(b.w) << 16);
  *(uint4*)(dst + i) = p;
}

// ---------------- RMSNorm 1: f32 in -> bf16 normed out ----------------
__global__ __launch_bounds__(256)
void k_rmsnorm1(const float* __restrict__ x, const float* __restrict__ w,
                u16* __restrict__ out) {
  const int t = blockIdx.x, tid = threadIdx.x;
  const size_t off = (size_t)t * D_ + tid * 8;
  float4 x0 = *(const float4*)(x + off);
  float4 x1 = *(const float4*)(x + off + 4);
  float v[8] = {x0.x, x0.y, x0.z, x0.w, x1.x, x1.y, x1.z, x1.w};
  float ss = 0.f;
  #pragma unroll
  for (int i = 0; i < 8; ++i) ss += v[i] * v[i];
  #pragma unroll
  for (int o = 32; o > 0; o >>= 1) ss += __shfl_xor(ss, o, 64);
  __shared__ float red[4];
  if ((tid & 63) == 0) red[tid >> 6] = ss;
  __syncthreads();
  const float tot = red[0] + red[1] + red[2] + red[3];
  const float rstd = 1.0f / sqrtf(tot / (float)D_ + 1e-6f);
  float4 w0 = *(const float4*)(w + tid * 8);
  float4 w1 = *(const float4*)(w + tid * 8 + 4);
  float wv[8] = {w0.x, w0.y, w0.z, w0.w, w1.x, w1.y, w1.z, w1.w};
  u32 hb[8];
  #pragma unroll
  for (int i = 0; i < 8; ++i) hb[i] = f2bf(v[i] * rstd * wv[i]);
  uint4 up;
  up.x = hb[0] | (hb[1] << 16); up.y = hb[2] | (hb[3] << 16);
  up.z = hb[4] | (hb[5] << 16); up.w = hb[6] | (hb[7] << 16);
  *(uint4*)(out + off) = up;
}

// -------- RMSNorm 2 + router (fp32 logits, exact argmax; h2 -> bf16) --
__global__ __launch_bounds__(256)
void k_rmsnorm2_router(const float* __restrict__ xin, const float* __restrict__ w,
                       const float* __restrict__ rw, const float* __restrict__ rb,
                       u16* __restrict__ h2, int* __restrict__ choice) {
  const int t = blockIdx.x, tid = threadIdx.x;
  const size_t off = (size_t)t * D_ + tid * 8;
  float4 x0 = *(const float4*)(xin + off);
  float4 x1 = *(const float4*)(xin + off + 4);
  float v[8] = {x0.x, x0.y, x0.z, x0.w, x1.x, x1.y, x1.z, x1.w};
  float ss = 0.f;
  #pragma unroll
  for (int i = 0; i < 8; ++i) ss += v[i] * v[i];
  #pragma unroll
  for (int o = 32; o > 0; o >>= 1) ss += __shfl_xor(ss, o, 64);
  __shared__ float red[4];
  __shared__ float rl[8];
  if ((tid & 63) == 0) red[tid >> 6] = ss;
  __syncthreads();
  const float tot = red[0] + red[1] + red[2] + red[3];
  const float rstd = 1.0f / sqrtf(tot / (float)D_ + 1e-6f);
  float4 w0 = *(const float4*)(w + tid * 8);
  float4 w1 = *(const float4*)(w + tid * 8 + 4);
  float wv[8] = {w0.x, w0.y, w0.z, w0.w, w1.x, w1.y, w1.z, w1.w};
  float4 ra = *(const float4*)(rw + tid * 8);
  float4 rb4 = *(const float4*)(rw + tid * 8 + 4);
  float4 rc = *(const float4*)(rw + D_ + tid * 8);
  float4 rd = *(const float4*)(rw + D_ + tid * 8 + 4);
  float r0[8] = {ra.x, ra.y, ra.z, ra.w, rb4.x, rb4.y, rb4.z, rb4.w};
  float r1[8] = {rc.x, rc.y, rc.z, rc.w, rd.x, rd.y, rd.z, rd.w};
  float l0 = 0.f, l1 = 0.f;
  u32 hb[8];
  #pragma unroll
  for (int i = 0; i < 8; ++i) {
    const float h = v[i] * rstd * wv[i];
    hb[i] = f2bf(h);
    l0 += h * r0[i];
    l1 += h * r1[i];
  }
  uint4 up;
  up.x = hb[0] | (hb[1] << 16); up.y = hb[2] | (hb[3] << 16);
  up.z = hb[4] | (hb[5] << 16); up.w = hb[6] | (hb[7] << 16);
  *(uint4*)(h2 + off) = up;
  #pragma unroll
  for (int o = 32; o > 0; o >>= 1) {
    l0 += __shfl_xor(l0, o, 64);
    l1 += __shfl_xor(l1, o, 64);
  }
  if ((tid & 63) == 0) { rl[tid >> 6] = l0; rl[4 + (tid >> 6)] = l1; }
  __syncthreads();
  if (tid == 0) {
    const float L0 = rl[0] + rl[1] + rl[2] + rl[3] + rb[0];
    const float L1 = rl[4] + rl[5] + rl[6] + rl[7] + rb[1];
    choice[t] = (L1 > L0) ? 1 : 0;   // tie -> 0, matches np argmax-first
  }
}

// ---------------- RoPE (fp64 trig, in-place on fp32 Q and K) ----------
__global__ __launch_bounds__(256)
void k_rope(float* __restrict__ Q, float* __restrict__ K) {
  const int t = blockIdx.x;
  const int s = t & (S_ - 1);
  const int d = threadIdx.x & 63;
  const int hq = threadIdx.x >> 6;
  const double inv = pow(10000.0, -(double)d / 64.0);
  const double ang = (double)s * inv;
  const float cf = (float)cos(ang);
  const float sf = (float)sin(ang);
  #pragma unroll
  for (int i = 0; i < 4; ++i) {
    const int h = hq * 4 + i;
    const size_t idx = (size_t)t * D_ + h * DH_ + d;
    float x1 = Q[idx], x2 = Q[idx + 64];
    Q[idx]      = x1 * cf - x2 * sf;
    Q[idx + 64] = x2 * cf + x1 * sf;
    float y1 = K[idx], y2 = K[idx + 64];
    K[idx]      = y1 * cf - y2 * sf;
    K[idx + 64] = y2 * cf + y1 * sf;
  }
}

// ---------------- fp32 flash attention (causal), bf16 ctx out ----------
__global__ __launch_bounds__(256)
void k_attn(const float* __restrict__ Q, const float* __restrict__ K,
            const float* __restrict__ V, u16* __restrict__ O) {
  __shared__ float Ks[32][144];
  __shared__ float Vs[32][144];
  const int qt = blockIdx.x, h = blockIdx.y, b = blockIdx.z;
  const int tid = threadIdx.x;
  const int ql = tid >> 2, c4 = tid & 3;
  const int qrow = qt * 64 + ql;
  const size_t rq = (size_t)(b * S_ + qrow);
  const float* qp = Q + rq * D_ + h * DH_ + c4 * 32;
  float4 q4[8], o4[8];
  #pragma unroll
  for (int i = 0; i < 8; ++i) {
    q4[i] = *(const float4*)(qp + i * 4);
    o4[i] = make_float4(0.f, 0.f, 0.f, 0.f);
  }
  float mrun = -INFINITY, lrun = 0.f;
  const float scale = 0.088388347648318447f;
  const int nkt = 2 * qt + 2;
  for (int jt = 0; jt < nkt; ++jt) {
    const int kv0 = jt * 32;
    #pragma unroll
    for (int u = 0; u < 4; ++u) {
      const int ci = u * 256 + tid;
      const int r = ci >> 5, lc = ci & 31;
      const int sc = (lc >> 3) * 36 + (lc & 7) * 4;
      const size_t g = (size_t)(b * S_ + kv0 + r) * D_ + h * DH_ + lc * 4;
      *(float4*)&Ks[r][sc] = *(const float4*)(K + g);
      *(float4*)&Vs[r][sc] = *(const float4*)(V + g);
    }
    __syncthreads();
    float s[32];
    #pragma unroll
    for (int kv = 0; kv < 32; ++kv) {
      float p = 0.f;
      #pragma unroll
      for (int d4 = 0; d4 < 8; ++d4) {
        float4 kk = *(const float4*)&Ks[kv][c4 * 36 + d4 * 4];
        p = fmaf(q4[d4].x, kk.x, p); p = fmaf(q4[d4].y, kk.y, p);
        p = fmaf(q4[d4].z, kk.z, p); p = fmaf(q4[d4].w, kk.w, p);
      }
      p += __shfl_xor(p, 1);
      p += __shfl_xor(p, 2);
      s[kv] = (kv0 + kv > qrow) ? -INFINITY : p * scale;
    }
    float mt = s[0];
    #pragma unroll
    for (int kv = 1; kv < 32; ++kv) mt = fmaxf(mt, s[kv]);
    const float mnew = fmaxf(mrun, mt);
    const float alpha = expf(mrun - mnew);
    float psum = 0.f;
    #pragma unroll
    for (int kv = 0; kv < 32; ++kv) { s[kv] = expf(s[kv] - mnew); psum += s[kv]; }
    lrun = lrun * alpha + psum;
    mrun = mnew;
    #pragma unroll
    for (int i = 0; i < 8; ++i) {
      o4[i].x *= alpha; o4[i].y *= alpha; o4[i].z *= alpha; o4[i].w *= alpha;
    }
    #pragma unroll
    for (int kv = 0; kv < 32; ++kv) {
      const float pv = s[kv];
      #pragma unroll
      for (int d4 = 0; d4 < 8; ++d4) {
        float4 vv = *(const float4*)&Vs[kv][c4 * 36 + d4 * 4];
        o4[d4].x = fmaf(pv, vv.x, o4[d4].x); o4[d4].y = fmaf(pv, vv.y, o4[d4].y);
        o4[d4].z = fmaf(pv, vv.z, o4[d4].z); o4[d4].w = fmaf(pv, vv.w, o4[d4].w);
      }
    }
    __syncthreads();
  }
  const float invl = 1.0f / lrun;
  u16* op = O + rq * D_ + h * DH_ + c4 * 32;
  u32 pk[16];
  #pragma unroll
  for (int d4 = 0; d4 < 8; ++d4) {
    pk[d4 * 2]     = f2bf(o4[d4].x * invl) | ((u32)f2bf(o4[d4].y * invl) << 16);
    pk[d4 * 2 + 1] = f2bf(o4[d4].z * invl) | ((u32)f2bf(o4[d4].w * invl) << 16);
  }
  #pragma unroll
  for (int d4 = 0; d4 < 4; ++d4) {
    uint4 w;
    w.x = pk[d4 * 4]; w.y = pk[d4 * 4 + 1]; w.z = pk[d4 * 4 + 2]; w.w = pk[d4 * 4 + 3];
    *(uint4*)(op + d4 * 8) = w;
  }
}

// ------- bf16 MFMA GEMM, fp32 out: C = A[M,K] * W[N,K]^T (+epilogue) ---
// EPI 0: C[idx] = acc + bias[col]      (QKV projections)
// EPI 1: C[idx] = acc + resf[idx]      (wo + residual)
template<int EPI>
__global__ __launch_bounds__(256)
void k_lin_bf16(const u16* __restrict__ A, const u16* __restrict__ W,
                const float* __restrict__ bias, const float* __restrict__ resf,
                float* __restrict__ C, int N, int K) {
  __shared__ u16 As[128 * 32];
  __shared__ u16 Bs[128 * 32];
  const int tid = threadIdx.x;
  const int wave = tid >> 6, lane = tid & 63;
  const int quad = lane >> 4, l16 = lane & 15;
  const int m0 = blockIdx.y * 128, n0 = blockIdx.x * 128;
  const int wm = (wave >> 1) * 64, wn = (wave & 1) * 64;
  f32x4 acc[4][4];
  #pragma unroll
  for (int i = 0; i < 4; ++i)
    #pragma unroll
    for (int j = 0; j < 4; ++j) acc[i][j] = 0;

  for (int k0 = 0; k0 < K; k0 += 32) {
    #pragma unroll
    for (int c = 0; c < 2; ++c) {
      const int ci = (c * 4 + wave) * 64 + lane;
      const int row = ci >> 2, ko = (ci & 3) << 3;
      __builtin_amdgcn_global_load_lds(
          (const __attribute__((address_space(1))) void*)(A + (size_t)(m0 + row) * K + k0 + ko),
          (__attribute__((address_space(3))) void*)(As + (size_t)(c * 4 + wave) * 512),
          16, 0, 0);
      __builtin_amdgcn_global_load_lds(
          (const __attribute__((address_space(1))) void*)(W + (size_t)(n0 + row) * K + k0 + ko),
          (__attribute__((address_space(3))) void*)(Bs + (size_t)(c * 4 + wave) * 512),
          16, 0, 0);
    }
    __syncthreads();
    bf16x8 af[4], bfr[4];
    #pragma unroll
    for (int i = 0; i < 4; ++i)
      af[i] = *(const bf16x8*)(As + (wm + i * 16 + l16) * 32 + quad * 8);
    #pragma unroll
    for (int j = 0; j < 4; ++j)
      bfr[j] = *(const bf16x8*)(Bs + (wn + j * 16 + l16) * 32 + quad * 8);
    #pragma unroll
    for (int i = 0; i < 4; ++i)
      #pragma unroll
      for (int j = 0; j < 4; ++j)
        acc[i][j] = __builtin_amdgcn_mfma_f32_16x16x32_bf16(af[i], bfr[j], acc[i][j], 0, 0, 0);
    __syncthreads();
  }

  #pragma unroll
  for (int i = 0; i < 4; ++i) {
    #pragma unroll
    for (int r = 0; r < 4; ++r) {
      const int row = m0 + wm + i * 16 + quad * 4 + r;
      #pragma unroll
      for (int j = 0; j < 4; ++j) {
        const int col = n0 + wn + j * 16 + l16;
        const float v = acc[i][j][r];
        const size_t idx = (size_t)row * N + col;
        if (EPI == 0) {
          C[idx] = v + bias[col];
        } else {
          C[idx] = v + resf[idx];
        }
      }
    }
  }
}

// ------- bf16 MFMA GEMM (m97 structure): C = A[M,K] * W[N,K]^T ---------
// EPI 0: C(bf16)[idx] = silu(acc)                        (gate)
// EPI 1: C(bf16)[idx] = acc * gbuf[idx]                  (up, in-place ok)
// EPI 2: C(f32)[idx]  = resf[idx] + (choice==0 ? acc:0)  (down e1)
// EPI 3: C(f32)[idx] += (choice==1 ? acc:0)              (down e2, RMW)
template<int EPI>
__global__ __launch_bounds__(256)
void k_moe_bf16(const u16* __restrict__ A, const u16* __restrict__ W,
                const u16* __restrict__ gbuf, const float* __restrict__ resf,
                const int* __restrict__ choice, void* Cv, int N, int K) {
  __shared__ u16 As[128 * 32];
  __shared__ u16 Bs[128 * 32];
  const int tid = threadIdx.x;
  const int wave = tid >> 6, lane = tid & 63;
  const int quad = lane >> 4, l16 = lane & 15;
  const int m0 = blockIdx.y * 128, n0 = blockIdx.x * 128;
  const int wm = (wave >> 1) * 64, wn = (wave & 1) * 64;
  f32x4 acc[4][4];
  #pragma unroll
  for (int i = 0; i < 4; ++i)
    #pragma unroll
    for (int j = 0; j < 4; ++j) acc[i][j] = 0;

  for (int k0 = 0; k0 < K; k0 += 32) {
    #pragma unroll
    for (int c = 0; c < 2; ++c) {
      const int ci = (c * 4 + wave) * 64 + lane;
      const int row = ci >> 2, ko = (ci & 3) << 3;
      __builtin_amdgcn_global_load_lds(
          (const __attribute__((address_space(1))) void*)(A + (size_t)(m0 + row) * K + k0 + ko),
          (__attribute__((address_space(3))) void*)(As + (size_t)(c * 4 + wave) * 512),
          16, 0, 0);
      __builtin_amdgcn_global_load_lds(
          (const __attribute__((address_space(1))) void*)(W + (size_t)(n0 + row) * K + k0 + ko),
          (__attribute__((address_space(3))) void*)(Bs + (size_t)(c * 4 + wave) * 512),
          16, 0, 0);
    }
    __syncthreads();
    bf16x8 af[4], bfr[4];
    #pragma unroll
    for (int i = 0; i < 4; ++i)
      af[i] = *(const bf16x8*)(As + (wm + i * 16 + l16) * 32 + quad * 8);
    #pragma unroll
    for (int j = 0; j < 4; ++j)
      bfr[j] = *(const bf16x8*)(Bs + (wn + j * 16 + l16) * 32 + quad * 8);
    #pragma unroll
    for (int i = 0; i < 4; ++i)
      #pragma unroll
      for (int j = 0; j < 4; ++j)
        acc[i][j] = __builtin_amdgcn_mfma_f32_16x16x32_bf16(af[i], bfr[j], acc[i][j], 0, 0, 0);
    __syncthreads();
  }

  #pragma unroll
  for (int i = 0; i < 4; ++i) {
    #pragma unroll
    for (int r = 0; r < 4; ++r) {
      const int row = m0 + wm + i * 16 + quad * 4 + r;
      #pragma unroll
      for (int j = 0; j < 4; ++j) {
        const int col = n0 + wn + j * 16 + l16;
        const float v = acc[i][j][r];
        const size_t idx = (size_t)row * N + col;
        if (EPI == 0) {
          ((u16*)Cv)[idx] = f2bf(v / (1.0f + expf(-v)));
        } else if (EPI == 1) {
          ((u16*)Cv)[idx] = f2bf(v * bf2f(gbuf[idx]));
        } else if (EPI == 2) {
          const float add = (choice[row] == 0) ? v : 0.0f;
          ((float*)Cv)[idx] = resf[idx] + add;
        } else {
          const float add = (choice[row] == 1) ? v : 0.0f;
          ((float*)Cv)[idx] += add;
        }
      }
    }
  }
}

// ---------------- launcher --------------------------------------------
extern "C" void kernel_launch(void* const* d_in, const int* in_sizes, int n_in,
                              void* d_out, int out_size, void* d_ws, size_t ws_size,
                              hipStream_t stream) {
  (void)in_sizes; (void)n_in; (void)out_size; (void)ws_size;
  const float* hidden = (const float*)d_in[0];
  const float* ln1w   = (const float*)d_in[1];
  const float* wq     = (const float*)d_in[2];
  const float* bq     = (const float*)d_in[3];
  const float* wk     = (const float*)d_in[4];
  const float* bk     = (const float*)d_in[5];
  const float* wv     = (const float*)d_in[6];
  const float* bv     = (const float*)d_in[7];
  const float* wo     = (const float*)d_in[8];
  const float* ln2w   = (const float*)d_in[9];
  const float* e1g    = (const float*)d_in[10];
  const float* e1u    = (const float*)d_in[11];
  const float* e1d    = (const float*)d_in[12];
  const float* e2g    = (const float*)d_in[13];
  const float* e2u    = (const float*)d_in[14];
  const float* e2d    = (const float*)d_in[15];
  const float* rw     = (const float*)d_in[16];
  const float* rb     = (const float*)d_in[17];
  float* out = (float*)d_out;
  char* ws = (char*)d_ws;

  const size_t MB = 1024 * 1024;
  // layout (MiB):
  // [0,16)    h1b  (bf16 normed hidden)
  // [16,48)   Qb (f32)           -> res2 (f32) after attention
  // [48,80)   Kb (f32)           -> h2b (bf16, 16MiB) + chs at [64,..) after attn
  // [80,112)  Vb (f32)           -> act bf16 43MiB spans [80,123) after wo-gemm
  // [112,128) ctxb (bf16)        (dead after wo-gemm; tail of act region)
  // [128,136) wlin bf16 (per D x D weight, reused 4x) -> wbf (21.5MiB MoE wt, reused 6x)
  u16*   h1b  = (u16*)(ws);
  float* Qb   = (float*)(ws + 16 * MB);
  float* Kb   = (float*)(ws + 48 * MB);
  float* Vb   = (float*)(ws + 80 * MB);
  u16*   ctxb = (u16*)(ws + 112 * MB);
  float* res2 = Qb;
  u16*   h2b  = (u16*)(ws + 48 * MB);
  int*   chs  = (int*)(ws + 64 * MB);
  u16*   act  = (u16*)(ws + 80 * MB);
  u16*   wlin = (u16*)(ws + 128 * MB);
  u16*   wbf  = (u16*)(ws + 128 * MB);

  k_rmsnorm1<<<MTOK, 256, 0, stream>>>(hidden, ln1w, h1b);

  const int WD = (D_ * D_) / 8 / 256;      // 2048 blocks per D x D weight
  const int WCONV = (F_ * D_) / 8 / 256;   // 5504 blocks per F x D weight
  dim3 gQKV(D_ / 128, MTOK / 128);

  k_f2bf<<<WD, 256, 0, stream>>>(wq, wlin);
  k_lin_bf16<0><<<gQKV, 256, 0, stream>>>(h1b, wlin, bq, nullptr, Qb, D_, D_);
  k_f2bf<<<WD, 256, 0, stream>>>(wk, wlin);
  k_lin_bf16<0><<<gQKV, 256, 0, stream>>>(h1b, wlin, bk, nullptr, Kb, D_, D_);
  k_f2bf<<<WD, 256, 0, stream>>>(wv, wlin);
  k_lin_bf16<0><<<gQKV, 256, 0, stream>>>(h1b, wlin, bv, nullptr, Vb, D_, D_);

  k_rope<<<MTOK, 256, 0, stream>>>(Qb, Kb);
  k_attn<<<dim3(S_ / 64, NH_, 2), 256, 0, stream>>>(Qb, Kb, Vb, ctxb);

  k_f2bf<<<WD, 256, 0, stream>>>(wo, wlin);
  k_lin_bf16<1><<<gQKV, 256, 0, stream>>>(ctxb, wlin, nullptr, hidden, res2, D_, D_);

  k_rmsnorm2_router<<<MTOK, 256, 0, stream>>>(res2, ln2w, rw, rb, h2b, chs);

  dim3 gFU(F_ / 128, MTOK / 128), gDN(D_ / 128, MTOK / 128);

  // expert 1
  k_f2bf<<<WCONV, 256, 0, stream>>>(e1g, wbf);
  k_moe_bf16<0><<<gFU, 256, 0, stream>>>(h2b, wbf, nullptr, nullptr, nullptr, act, F_, D_);
  k_f2bf<<<WCONV, 256, 0, stream>>>(e1u, wbf);
  k_moe_bf16<1><<<gFU, 256, 0, stream>>>(h2b, wbf, act, nullptr, nullptr, act, F_, D_);
  k_f2bf<<<WCONV, 256, 0, stream>>>(e1d, wbf);
  k_moe_bf16<2><<<gDN, 256, 0, stream>>>(act, wbf, nullptr, res2, chs, out, D_, F_);
  // expert 2
  k_f2bf<<<WCONV, 256, 0, stream>>>(e2g, wbf);
  k_moe_bf16<0><<<gFU, 256, 0, stream>>>(h2b, wbf, nullptr, nullptr, nullptr, act, F_, D_);
  k_f2bf<<<WCONV, 256, 0, stream>>>(e2u, wbf);
  k_moe_bf16<1><<<gFU, 256, 0, stream>>>(h2b, wbf, act, nullptr, nullptr, act, F_, D_);
  k_f2bf<<<WCONV, 256, 0, stream>>>(e2d, wbf);
  k_moe_bf16<3><<<gDN, 256, 0, stream>>>(act, wbf, nullptr, res2, chs, out, D_, F_);
}

// Round 2
// 2010.453 us; speedup vs baseline: 1.9865x; 1.9865x over previous
//
#include <hip/hip_runtime.h>
#include <math.h>

typedef unsigned short u16;
typedef unsigned int u32;

#define D_ 2048
#define S_ 2048
#define DH_ 128
#define NH_ 16
#define F_ 5504
#define MTOK 4096

typedef __bf16 bf16x8 __attribute__((ext_vector_type(8)));
typedef float f32x4 __attribute__((ext_vector_type(4)));

__device__ __forceinline__ float bf2f(u32 u) {
  union { u32 i; float f; } x; x.i = u << 16; return x.f;
}
__device__ __forceinline__ u16 f2bf(float f) {
  u32 x = __float_as_uint(f);
  return (u16)((x + 0x7fffu + ((x >> 16) & 1u)) >> 16);
}

// ---------------- fp32 -> bf16 elementwise convert (weights) ----------
__global__ __launch_bounds__(256)
void k_f2bf(const float* __restrict__ src, u16* __restrict__ dst) {
  const size_t i = ((size_t)blockIdx.x * 256 + threadIdx.x) * 8;
  float4 a = *(const float4*)(src + i);
  float4 b = *(const float4*)(src + i + 4);
  uint4 p;
  p.x = f2bf(a.x) | ((u32)f2bf(a.y) << 16);
  p.y = f2bf(a.z) | ((u32)f2bf(a.w) << 16);
  p.z = f2bf(b.x) | ((u32)f2bf(b.y) << 16);
  p.w = f2bf(b.z) | ((u32)f2bf(b.w) << 16);
  *(uint4*)(dst + i) = p;
}

// ---------------- RMSNorm 1: f32 in -> bf16 normed out ----------------
__global__ __launch_bounds__(256)
void k_rmsnorm1(const float* __restrict__ x, const float* __restrict__ w,
                u16* __restrict__ out) {
  const int t = blockIdx.x, tid = threadIdx.x;
  const size_t off = (size_t)t * D_ + tid * 8;
  float4 x0 = *(const float4*)(x + off);
  float4 x1 = *(const float4*)(x + off + 4);
  float v[8] = {x0.x, x0.y, x0.z, x0.w, x1.x, x1.y, x1.z, x1.w};
  float ss = 0.f;
  #pragma unroll
  for (int i = 0; i < 8; ++i) ss += v[i] * v[i];
  #pragma unroll
  for (int o = 32; o > 0; o >>= 1) ss += __shfl_xor(ss, o, 64);
  __shared__ float red[4];
  if ((tid & 63) == 0) red[tid >> 6] = ss;
  __syncthreads();
  const float tot = red[0] + red[1] + red[2] + red[3];
  const float rstd = 1.0f / sqrtf(tot / (float)D_ + 1e-6f);
  float4 w0 = *(const float4*)(w + tid * 8);
  float4 w1 = *(const float4*)(w + tid * 8 + 4);
  float wv[8] = {w0.x, w0.y, w0.z, w0.w, w1.x, w1.y, w1.z, w1.w};
  u32 hb[8];
  #pragma unroll
  for (int i = 0; i < 8; ++i) hb[i] = f2bf(v[i] * rstd * wv[i]);
  uint4 up;
  up.x = hb[0] | (hb[1] << 16); up.y = hb[2] | (hb[3] << 16);
  up.z = hb[4] | (hb[5] << 16); up.w = hb[6] | (hb[7] << 16);
  *(uint4*)(out + off) = up;
}

// -------- RMSNorm 2 + router (fp32 logits, exact argmax; h2 -> bf16) --
__global__ __launch_bounds__(256)
void k_rmsnorm2_router(const float* __restrict__ xin, const float* __restrict__ w,
                       const float* __restrict__ rw, const float* __restrict__ rb,
                       u16* __restrict__ h2, int* __restrict__ choice) {
  const int t = blockIdx.x, tid = threadIdx.x;
  const size_t off = (size_t)t * D_ + tid * 8;
  float4 x0 = *(const float4*)(xin + off);
  float4 x1 = *(const float4*)(xin + off + 4);
  float v[8] = {x0.x, x0.y, x0.z, x0.w, x1.x, x1.y, x1.z, x1.w};
  float ss = 0.f;
  #pragma unroll
  for (int i = 0; i < 8; ++i) ss += v[i] * v[i];
  #pragma unroll
  for (int o = 32; o > 0; o >>= 1) ss += __shfl_xor(ss, o, 64);
  __shared__ float red[4];
  __shared__ float rl[8];
  if ((tid & 63) == 0) red[tid >> 6] = ss;
  __syncthreads();
  const float tot = red[0] + red[1] + red[2] + red[3];
  const float rstd = 1.0f / sqrtf(tot / (float)D_ + 1e-6f);
  float4 w0 = *(const float4*)(w + tid * 8);
  float4 w1 = *(const float4*)(w + tid * 8 + 4);
  float wv[8] = {w0.x, w0.y, w0.z, w0.w, w1.x, w1.y, w1.z, w1.w};
  float4 ra = *(const float4*)(rw + tid * 8);
  float4 rb4 = *(const float4*)(rw + tid * 8 + 4);
  float4 rc = *(const float4*)(rw + D_ + tid * 8);
  float4 rd = *(const float4*)(rw + D_ + tid * 8 + 4);
  float r0[8] = {ra.x, ra.y, ra.z, ra.w, rb4.x, rb4.y, rb4.z, rb4.w};
  float r1[8] = {rc.x, rc.y, rc.z, rc.w, rd.x, rd.y, rd.z, rd.w};
  float l0 = 0.f, l1 = 0.f;
  u32 hb[8];
  #pragma unroll
  for (int i = 0; i < 8; ++i) {
    const float h = v[i] * rstd * wv[i];
    hb[i] = f2bf(h);
    l0 += h * r0[i];
    l1 += h * r1[i];
  }
  uint4 up;
  up.x = hb[0] | (hb[1] << 16); up.y = hb[2] | (hb[3] << 16);
  up.z = hb[4] | (hb[5] << 16); up.w = hb[6] | (hb[7] << 16);
  *(uint4*)(h2 + off) = up;
  #pragma unroll
  for (int o = 32; o > 0; o >>= 1) {
    l0 += __shfl_xor(l0, o, 64);
    l1 += __shfl_xor(l1, o, 64);
  }
  if ((tid & 63) == 0) { rl[tid >> 6] = l0; rl[4 + (tid >> 6)] = l1; }
  __syncthreads();
  if (tid == 0) {
    const float L0 = rl[0] + rl[1] + rl[2] + rl[3] + rb[0];
    const float L1 = rl[4] + rl[5] + rl[6] + rl[7] + rb[1];
    choice[t] = (L1 > L0) ? 1 : 0;   // tie -> 0, matches np argmax-first
  }
}

// ------- RoPE (fp64 trig): fp32 Q,K in -> bf16 out, Q scaled 1/sqrt(DH)
__global__ __launch_bounds__(256)
void k_rope_bf(const float* __restrict__ Q, const float* __restrict__ K,
               u16* __restrict__ Qo, u16* __restrict__ Ko) {
  const int t = blockIdx.x;
  const int s = t & (S_ - 1);
  const int d = threadIdx.x & 63;
  const int hq = threadIdx.x >> 6;
  const double inv = pow(10000.0, -(double)d / 64.0);
  const double ang = (double)s * inv;
  const float cf = (float)cos(ang);
  const float sf = (float)sin(ang);
  const float sc = 0.088388347648318447f;   // 1/sqrt(128) folded into Q
  #pragma unroll
  for (int i = 0; i < 4; ++i) {
    const int h = hq * 4 + i;
    const size_t idx = (size_t)t * D_ + h * DH_ + d;
    float x1 = Q[idx], x2 = Q[idx + 64];
    Qo[idx]      = f2bf((x1 * cf - x2 * sf) * sc);
    Qo[idx + 64] = f2bf((x2 * cf + x1 * sf) * sc);
    float y1 = K[idx], y2 = K[idx + 64];
    Ko[idx]      = f2bf(y1 * cf - y2 * sf);
    Ko[idx + 64] = f2bf(y2 * cf + y1 * sf);
  }
}

// ---------------- bf16 MFMA flash attention (causal) -------------------
// 4 waves/block; 64 q-rows/block (16 per wave); KV tile = 64.
// Q scaled by 1/sqrt(DH) already. Softmax fp32, P bf16, PV fp32 acc.
__global__ __launch_bounds__(256)
void k_attn_mfma(const u16* __restrict__ Qbf, const u16* __restrict__ Kbf,
                 const u16* __restrict__ Vbf, u16* __restrict__ O) {
  __shared__ u16 Ks[64 * 128];        // K tile, chunk-swizzled: p = (c&8)|((c&7)^(row&7))
  __shared__ u16 Vt[128 * 64];        // V^T tile, chunk-swz: p = c ^ (d&7) ^ ((d>>5)&3)
  __shared__ u16 Ps[4 * 16 * 64];     // per-wave P, chunk-swz: p = c ^ (q&7) ^ (q>>3)
  const int qx = blockIdx.x, h = blockIdx.y, b = blockIdx.z;
  const int qt = (qx & 1) ? (31 - (qx >> 1)) : (qx >> 1);   // pair long+short tiles
  const int tid = threadIdx.x;
  const int w = tid >> 6, lane = tid & 63;
  const int quad = lane >> 4, l16 = lane & 15;

  // Q fragments in registers (A operand rows = l16)
  const int q0 = qt * 64 + w * 16;
  const size_t qrow = (size_t)(b * S_ + q0 + l16) * D_ + h * DH_;
  bf16x8 qf[4];
  #pragma unroll
  for (int kd = 0; kd < 4; ++kd)
    qf[kd] = *(const bf16x8*)(Qbf + qrow + kd * 32 + quad * 8);

  f32x4 acc_o[8];
  #pragma unroll
  for (int i = 0; i < 8; ++i) acc_o[i] = 0;
  float mrun[4], lrun[4];
  #pragma unroll
  for (int r = 0; r < 4; ++r) { mrun[r] = -INFINITY; lrun[r] = 0.f; }

  const int nkt = qt + 1;
  const int vk = tid >> 2;              // V stage: this thread's kv row
  const int vd0 = (tid & 3) * 32;       // and d-range base

  for (int jt = 0; jt < nkt; ++jt) {
    const int kv0 = jt * 64;
    // --- stage K via global_load_lds, pre-swizzled source (rule 21) ---
    #pragma unroll
    for (int i = 0; i < 4; ++i) {
      const int slot = w * 256 + i * 64 + lane;
      const int r = slot >> 4, c = slot & 15;
      const int clog = (c & 8) | ((c & 7) ^ (r & 7));
      __builtin_amdgcn_global_load_lds(
        (const __attribute__((address_space(1))) void*)
          (Kbf + (size_t)(b * S_ + kv0 + r) * D_ + h * DH_ + clog * 8),
        (__attribute__((address_space(3))) void*)(Ks + (w * 256 + i * 64) * 8),
        16, 0, 0);
    }
    // --- stage V transposed (bf16 scatter, bank-swizzled) ---
    #pragma unroll
    for (int rr = 0; rr < 4; ++rr) {
      const int d0 = vd0 + rr * 8;
      bf16x8 vv = *(const bf16x8*)(Vbf + (size_t)(b * S_ + kv0 + vk) * D_ + h * DH_ + d0);
      const u16* pv = (const u16*)&vv;
      #pragma unroll
      for (int e = 0; e < 8; ++e) {
        const int d = d0 + e;
        Vt[d * 64 + ((((vk >> 3) ^ (d & 7) ^ ((d >> 5) & 3)) & 7) << 3) + (vk & 7)] = pv[e];
      }
    }
    __syncthreads();

    // --- QK^T: S[16q][64kv] per wave ---
    f32x4 st[4];
    #pragma unroll
    for (int nt = 0; nt < 4; ++nt) st[nt] = 0;
    #pragma unroll
    for (int kd = 0; kd < 4; ++kd) {
      #pragma unroll
      for (int nt = 0; nt < 4; ++nt) {
        const int kvr = nt * 16 + l16;
        const int c = kd * 4 + quad;
        const int p = (c & 8) | ((c & 7) ^ (kvr & 7));
        bf16x8 kf = *(const bf16x8*)(Ks + kvr * 128 + p * 8);
        st[nt] = __builtin_amdgcn_mfma_f32_16x16x32_bf16(qf[kd], kf, st[nt], 0, 0, 0);
      }
    }
    // --- causal mask (diagonal tile only) ---
    if (jt == qt) {
      #pragma unroll
      for (int nt = 0; nt < 4; ++nt) {
        const int kv = kv0 + nt * 16 + l16;
        #pragma unroll
        for (int r = 0; r < 4; ++r) {
          const int q = qt * 64 + w * 16 + quad * 4 + r;
          if (kv > q) st[nt][r] = -INFINITY;
        }
      }
    }
    // --- online softmax: rows = quad*4+r, reduce over l16 lanes ---
    float mx[4];
    #pragma unroll
    for (int r = 0; r < 4; ++r)
      mx[r] = fmaxf(fmaxf(st[0][r], st[1][r]), fmaxf(st[2][r], st[3][r]));
    #pragma unroll
    for (int o = 1; o < 16; o <<= 1) {
      #pragma unroll
      for (int r = 0; r < 4; ++r) mx[r] = fmaxf(mx[r], __shfl_xor(mx[r], o, 64));
    }
    float alpha[4], psum[4];
    #pragma unroll
    for (int r = 0; r < 4; ++r) {
      const float mnew = fmaxf(mrun[r], mx[r]);
      alpha[r] = expf(mrun[r] - mnew);
      mrun[r] = mnew;
      psum[r] = 0.f;
    }
    u16 pb[4][4];
    #pragma unroll
    for (int nt = 0; nt < 4; ++nt) {
      #pragma unroll
      for (int r = 0; r < 4; ++r) {
        const float p = expf(st[nt][r] - mrun[r]);
        psum[r] += p;
        pb[nt][r] = f2bf(p);
      }
    }
    #pragma unroll
    for (int o = 1; o < 16; o <<= 1) {
      #pragma unroll
      for (int r = 0; r < 4; ++r) psum[r] += __shfl_xor(psum[r], o, 64);
    }
    #pragma unroll
    for (int r = 0; r < 4; ++r) lrun[r] = lrun[r] * alpha[r] + psum[r];
    #pragma unroll
    for (int i = 0; i < 8; ++i) {
      #pragma unroll
      for (int r = 0; r < 4; ++r) acc_o[i][r] *= alpha[r];
    }
    // --- write P to per-wave private LDS region (no cross-wave sync) ---
    const int wbase = w * 1024;
    #pragma unroll
    for (int nt = 0; nt < 4; ++nt) {
      #pragma unroll
      for (int r = 0; r < 4; ++r) {
        const int q = quad * 4 + r;
        const int cc = ((nt * 2 + (l16 >> 3)) ^ (q & 7) ^ (q >> 3)) & 7;
        Ps[wbase + q * 64 + cc * 8 + (l16 & 7)] = pb[nt][r];
      }
    }
    // --- PV: O[16q][128d] += P[16q][64kv] * V[64kv][128d] ---
    #pragma unroll
    for (int ks = 0; ks < 2; ++ks) {
      const int cP = ((ks * 4 + quad) ^ (l16 & 7) ^ (l16 >> 3)) & 7;
      bf16x8 pa = *(const bf16x8*)(Ps + wbase + l16 * 64 + cP * 8);
      #pragma unroll
      for (int nt = 0; nt < 8; ++nt) {
        const int d = nt * 16 + l16;
        const int cV = ((ks * 4 + quad) ^ (d & 7) ^ ((d >> 5) & 3)) & 7;
        bf16x8 vf = *(const bf16x8*)(Vt + d * 64 + cV * 8);
        acc_o[nt] = __builtin_amdgcn_mfma_f32_16x16x32_bf16(pa, vf, acc_o[nt], 0, 0, 0);
      }
    }
    __syncthreads();
  }
  // --- epilogue: normalize, write bf16 ctx ---
  float invl[4];
  #pragma unroll
  for (int r = 0; r < 4; ++r) invl[r] = 1.0f / lrun[r];
  #pragma unroll
  for (int r = 0; r < 4; ++r) {
    const size_t orow = (size_t)(b * S_ + qt * 64 + w * 16 + quad * 4 + r) * D_ + h * DH_;
    #pragma unroll
    for (int nt = 0; nt < 8; ++nt)
      O[orow + nt * 16 + l16] = f2bf(acc_o[nt][r] * invl[r]);
  }
}

// ------- bf16 MFMA GEMM, C = A[M,K] * W[N,K]^T (+epilogue) -------------
// EPI 0: C(f32)[idx] = acc + bias[col]      (Q,K projections)
// EPI 1: C(f32)[idx] = acc + resf[idx]      (wo + residual)
// EPI 2: C(bf16)[idx] = acc + bias[col]     (V projection, direct bf16)
template<int EPI>
__global__ __launch_bounds__(256)
void k_lin_bf16(const u16* __restrict__ A, const u16* __restrict__ W,
                const float* __restrict__ bias, const float* __restrict__ resf,
                void* Cv, int N, int K) {
  __shared__ u16 As[128 * 32];
  __shared__ u16 Bs[128 * 32];
  const int tid = threadIdx.x;
  const int wave = tid >> 6, lane = tid & 63;
  const int quad = lane >> 4, l16 = lane & 15;
  const int m0 = blockIdx.y * 128, n0 = blockIdx.x * 128;
  const int wm = (wave >> 1) * 64, wn = (wave & 1) * 64;
  f32x4 acc[4][4];
  #pragma unroll
  for (int i = 0; i < 4; ++i)
    #pragma unroll
    for (int j = 0; j < 4; ++j) acc[i][j] = 0;

  for (int k0 = 0; k0 < K; k0 += 32) {
    #pragma unroll
    for (int c = 0; c < 2; ++c) {
      const int ci = (c * 4 + wave) * 64 + lane;
      const int row = ci >> 2, ko = (ci & 3) << 3;
      __builtin_amdgcn_global_load_lds(
          (const __attribute__((address_space(1))) void*)(A + (size_t)(m0 + row) * K + k0 + ko),
          (__attribute__((address_space(3))) void*)(As + (size_t)(c * 4 + wave) * 512),
          16, 0, 0);
      __builtin_amdgcn_global_load_lds(
          (const __attribute__((address_space(1))) void*)(W + (size_t)(n0 + row) * K + k0 + ko),
          (__attribute__((address_space(3))) void*)(Bs + (size_t)(c * 4 + wave) * 512),
          16, 0, 0);
    }
    __syncthreads();
    bf16x8 af[4], bfr[4];
    #pragma unroll
    for (int i = 0; i < 4; ++i)
      af[i] = *(const bf16x8*)(As + (wm + i * 16 + l16) * 32 + quad * 8);
    #pragma unroll
    for (int j = 0; j < 4; ++j)
      bfr[j] = *(const bf16x8*)(Bs + (wn + j * 16 + l16) * 32 + quad * 8);
    #pragma unroll
    for (int i = 0; i < 4; ++i)
      #pragma unroll
      for (int j = 0; j < 4; ++j)
        acc[i][j] = __builtin_amdgcn_mfma_f32_16x16x32_bf16(af[i], bfr[j], acc[i][j], 0, 0, 0);
    __syncthreads();
  }

  #pragma unroll
  for (int i = 0; i < 4; ++i) {
    #pragma unroll
    for (int r = 0; r < 4; ++r) {
      const int row = m0 + wm + i * 16 + quad * 4 + r;
      #pragma unroll
      for (int j = 0; j < 4; ++j) {
        const int col = n0 + wn + j * 16 + l16;
        const float v = acc[i][j][r];
        const size_t idx = (size_t)row * N + col;
        if (EPI == 0) {
          ((float*)Cv)[idx] = v + bias[col];
        } else if (EPI == 1) {
          ((float*)Cv)[idx] = v + resf[idx];
        } else {
          ((u16*)Cv)[idx] = f2bf(v + bias[col]);
        }
      }
    }
  }
}

// ------- bf16 MFMA GEMM (m97 structure): C = A[M,K] * W[N,K]^T ---------
// EPI 0: C(bf16)[idx] = silu(acc)                        (gate)
// EPI 1: C(bf16)[idx] = acc * gbuf[idx]                  (up, in-place ok)
// EPI 2: C(f32)[idx]  = resf[idx] + (choice==0 ? acc:0)  (down e1)
// EPI 3: C(f32)[idx] += (choice==1 ? acc:0)              (down e2, RMW)
template<int EPI>
__global__ __launch_bounds__(256)
void k_moe_bf16(const u16* __restrict__ A, const u16* __restrict__ W,
                const u16* __restrict__ gbuf, const float* __restrict__ resf,
                const int* __restrict__ choice, void* Cv, int N, int K) {
  __shared__ u16 As[128 * 32];
  __shared__ u16 Bs[128 * 32];
  const int tid = threadIdx.x;
  const int wave = tid >> 6, lane = tid & 63;
  const int quad = lane >> 4, l16 = lane & 15;
  const int m0 = blockIdx.y * 128, n0 = blockIdx.x * 128;
  const int wm = (wave >> 1) * 64, wn = (wave & 1) * 64;
  f32x4 acc[4][4];
  #pragma unroll
  for (int i = 0; i < 4; ++i)
    #pragma unroll
    for (int j = 0; j < 4; ++j) acc[i][j] = 0;

  for (int k0 = 0; k0 < K; k0 += 32) {
    #pragma unroll
    for (int c = 0; c < 2; ++c) {
      const int ci = (c * 4 + wave) * 64 + lane;
      const int row = ci >> 2, ko = (ci & 3) << 3;
      __builtin_amdgcn_global_load_lds(
          (const __attribute__((address_space(1))) void*)(A + (size_t)(m0 + row) * K + k0 + ko),
          (__attribute__((address_space(3))) void*)(As + (size_t)(c * 4 + wave) * 512),
          16, 0, 0);
      __builtin_amdgcn_global_load_lds(
          (const __attribute__((address_space(1))) void*)(W + (size_t)(n0 + row) * K + k0 + ko),
          (__attribute__((address_space(3))) void*)(Bs + (size_t)(c * 4 + wave) * 512),
          16, 0, 0);
    }
    __syncthreads();
    bf16x8 af[4], bfr[4];
    #pragma unroll
    for (int i = 0; i < 4; ++i)
      af[i] = *(const bf16x8*)(As + (wm + i * 16 + l16) * 32 + quad * 8);
    #pragma unroll
    for (int j = 0; j < 4; ++j)
      bfr[j] = *(const bf16x8*)(Bs + (wn + j * 16 + l16) * 32 + quad * 8);
    #pragma unroll
    for (int i = 0; i < 4; ++i)
      #pragma unroll
      for (int j = 0; j < 4; ++j)
        acc[i][j] = __builtin_amdgcn_mfma_f32_16x16x32_bf16(af[i], bfr[j], acc[i][j], 0, 0, 0);
    __syncthreads();
  }

  #pragma unroll
  for (int i = 0; i < 4; ++i) {
    #pragma unroll
    for (int r = 0; r < 4; ++r) {
      const int row = m0 + wm + i * 16 + quad * 4 + r;
      #pragma unroll
      for (int j = 0; j < 4; ++j) {
        const int col = n0 + wn + j * 16 + l16;
        const float v = acc[i][j][r];
        const size_t idx = (size_t)row * N + col;
        if (EPI == 0) {
          ((u16*)Cv)[idx] = f2bf(v / (1.0f + expf(-v)));
        } else if (EPI == 1) {
          ((u16*)Cv)[idx] = f2bf(v * bf2f(gbuf[idx]));
        } else if (EPI == 2) {
          const float add = (choice[row] == 0) ? v : 0.0f;
          ((float*)Cv)[idx] = resf[idx] + add;
        } else {
          const float add = (choice[row] == 1) ? v : 0.0f;
          ((float*)Cv)[idx] += add;
        }
      }
    }
  }
}

// ---------------- launcher --------------------------------------------
extern "C" void kernel_launch(void* const* d_in, const int* in_sizes, int n_in,
                              void* d_out, int out_size, void* d_ws, size_t ws_size,
                              hipStream_t stream) {
  (void)in_sizes; (void)n_in; (void)out_size; (void)ws_size;
  const float* hidden = (const float*)d_in[0];
  const float* ln1w   = (const float*)d_in[1];
  const float* wq     = (const float*)d_in[2];
  const float* bq     = (const float*)d_in[3];
  const float* wk     = (const float*)d_in[4];
  const float* bk     = (const float*)d_in[5];
  const float* wv     = (const float*)d_in[6];
  const float* bv     = (const float*)d_in[7];
  const float* wo     = (const float*)d_in[8];
  const float* ln2w   = (const float*)d_in[9];
  const float* e1g    = (const float*)d_in[10];
  const float* e1u    = (const float*)d_in[11];
  const float* e1d    = (const float*)d_in[12];
  const float* e2g    = (const float*)d_in[13];
  const float* e2u    = (const float*)d_in[14];
  const float* e2d    = (const float*)d_in[15];
  const float* rw     = (const float*)d_in[16];
  const float* rb     = (const float*)d_in[17];
  float* out = (float*)d_out;
  char* ws = (char*)d_ws;

  const size_t MB = 1024 * 1024;
  // layout (MiB):
  // [0,16)    h1b bf16
  // [16,48)   Qb f32            -> res2 f32 after attention
  // [48,80)   Kb f32            -> h2b bf16 [48,64) + chs [64,65) after attn
  // [80,96)   Qbf bf16          -> act bf16 [80,123) after attn
  // [96,112)  Kbf bf16              (same act region)
  // [112,128) Vbf bf16              (same act region)
  // [128,144) ctxb bf16         (dead after wo gemm)
  // [144,152) wlin bf16 (DxD, reused 4x) -> wbf bf16 [144,166) (MoE, reused 6x)
  u16*   h1b  = (u16*)(ws);
  float* Qb   = (float*)(ws + 16 * MB);
  float* Kb   = (float*)(ws + 48 * MB);
  u16*   Qbf  = (u16*)(ws + 80 * MB);
  u16*   Kbf  = (u16*)(ws + 96 * MB);
  u16*   Vbf  = (u16*)(ws + 112 * MB);
  u16*   ctxb = (u16*)(ws + 128 * MB);
  float* res2 = Qb;
  u16*   h2b  = (u16*)(ws + 48 * MB);
  int*   chs  = (int*)(ws + 64 * MB);
  u16*   act  = (u16*)(ws + 80 * MB);
  u16*   wlin = (u16*)(ws + 144 * MB);
  u16*   wbf  = (u16*)(ws + 144 * MB);

  k_rmsnorm1<<<MTOK, 256, 0, stream>>>(hidden, ln1w, h1b);

  const int WD = (D_ * D_) / 8 / 256;      // 2048 blocks per D x D weight
  const int WCONV = (F_ * D_) / 8 / 256;   // 5504 blocks per F x D weight
  dim3 gQKV(D_ / 128, MTOK / 128);

  k_f2bf<<<WD, 256, 0, stream>>>(wq, wlin);
  k_lin_bf16<0><<<gQKV, 256, 0, stream>>>(h1b, wlin, bq, nullptr, Qb, D_, D_);
  k_f2bf<<<WD, 256, 0, stream>>>(wk, wlin);
  k_lin_bf16<0><<<gQKV, 256, 0, stream>>>(h1b, wlin, bk, nullptr, Kb, D_, D_);
  k_f2bf<<<WD, 256, 0, stream>>>(wv, wlin);
  k_lin_bf16<2><<<gQKV, 256, 0, stream>>>(h1b, wlin, bv, nullptr, Vbf, D_, D_);

  k_rope_bf<<<MTOK, 256, 0, stream>>>(Qb, Kb, Qbf, Kbf);
  k_attn_mfma<<<dim3(32, NH_, 2), 256, 0, stream>>>(Qbf, Kbf, Vbf, ctxb);

  k_f2bf<<<WD, 256, 0, stream>>>(wo, wlin);
  k_lin_bf16<1><<<gQKV, 256, 0, stream>>>(ctxb, wlin, nullptr, hidden, res2, D_, D_);

  k_rmsnorm2_router<<<MTOK, 256, 0, stream>>>(res2, ln2w, rw, rb, h2b, chs);

  dim3 gFU(F_ / 128, MTOK / 128), gDN(D_ / 128, MTOK / 128);

  // expert 1
  k_f2bf<<<WCONV, 256, 0, stream>>>(e1g, wbf);
  k_moe_bf16<0><<<gFU, 256, 0, stream>>>(h2b, wbf, nullptr, nullptr, nullptr, act, F_, D_);
  k_f2bf<<<WCONV, 256, 0, stream>>>(e1u, wbf);
  k_moe_bf16<1><<<gFU, 256, 0, stream>>>(h2b, wbf, act, nullptr, nullptr, act, F_, D_);
  k_f2bf<<<WCONV, 256, 0, stream>>>(e1d, wbf);
  k_moe_bf16<2><<<gDN, 256, 0, stream>>>(act, wbf, nullptr, res2, chs, out, D_, F_);
  // expert 2
  k_f2bf<<<WCONV, 256, 0, stream>>>(e2g, wbf);
  k_moe_bf16<0><<<gFU, 256, 0, stream>>>(h2b, wbf, nullptr, nullptr, nullptr, act, F_, D_);
  k_f2bf<<<WCONV, 256, 0, stream>>>(e2u, wbf);
  k_moe_bf16<1><<<gFU, 256, 0, stream>>>(h2b, wbf, act, nullptr, nullptr, act, F_, D_);
  k_f2bf<<<WCONV, 256, 0, stream>>>(e2d, wbf);
  k_moe_bf16<3><<<gDN, 256, 0, stream>>>(act, wbf, nullptr, res2, chs, out, D_, F_);
}

// Round 4
// 1680.195 us; speedup vs baseline: 2.3769x; 1.1966x over previous
//
#include <hip/hip_runtime.h>
#include <math.h>

typedef unsigned short u16;
typedef unsigned int u32;

#define D_ 2048
#define S_ 2048
#define DH_ 128
#define NH_ 16
#define F_ 5504
#define MTOK 4096

typedef __bf16 bf16x8 __attribute__((ext_vector_type(8)));
typedef float f32x4 __attribute__((ext_vector_type(4)));

__device__ __forceinline__ float bf2f(u32 u) {
  union { u32 i; float f; } x; x.i = u << 16; return x.f;
}
__device__ __forceinline__ u16 f2bf(float f) {
  u32 x = __float_as_uint(f);
  return (u16)((x + 0x7fffu + ((x >> 16) & 1u)) >> 16);
}

// ---------------- fp32 -> bf16 elementwise convert (weights) ----------
__global__ __launch_bounds__(256)
void k_f2bf(const float* __restrict__ src, u16* __restrict__ dst) {
  const size_t i = ((size_t)blockIdx.x * 256 + threadIdx.x) * 8;
  float4 a = *(const float4*)(src + i);
  float4 b = *(const float4*)(src + i + 4);
  uint4 p;
  p.x = f2bf(a.x) | ((u32)f2bf(a.y) << 16);
  p.y = f2bf(a.z) | ((u32)f2bf(a.w) << 16);
  p.z = f2bf(b.x) | ((u32)f2bf(b.y) << 16);
  p.w = f2bf(b.z) | ((u32)f2bf(b.w) << 16);
  *(uint4*)(dst + i) = p;
}

// ---------------- MoE routing init: zero counters + idx ----------------
__global__ __launch_bounds__(256)
void k_moe_init(int* __restrict__ cnt, int* __restrict__ idx) {
  const int tid = threadIdx.x;
  if (tid < 2) cnt[tid] = 0;
  for (int i = tid; i < 2 * MTOK; i += 256) idx[i] = 0;
}

// ---------------- RMSNorm 1: f32 in -> bf16 normed out ----------------
__global__ __launch_bounds__(256)
void k_rmsnorm1(const float* __restrict__ x, const float* __restrict__ w,
                u16* __restrict__ out) {
  const int t = blockIdx.x, tid = threadIdx.x;
  const size_t off = (size_t)t * D_ + tid * 8;
  float4 x0 = *(const float4*)(x + off);
  float4 x1 = *(const float4*)(x + off + 4);
  float v[8] = {x0.x, x0.y, x0.z, x0.w, x1.x, x1.y, x1.z, x1.w};
  float ss = 0.f;
  #pragma unroll
  for (int i = 0; i < 8; ++i) ss += v[i] * v[i];
  #pragma unroll
  for (int o = 32; o > 0; o >>= 1) ss += __shfl_xor(ss, o, 64);
  __shared__ float red[4];
  if ((tid & 63) == 0) red[tid >> 6] = ss;
  __syncthreads();
  const float tot = red[0] + red[1] + red[2] + red[3];
  const float rstd = 1.0f / sqrtf(tot / (float)D_ + 1e-6f);
  float4 w0 = *(const float4*)(w + tid * 8);
  float4 w1 = *(const float4*)(w + tid * 8 + 4);
  float wv[8] = {w0.x, w0.y, w0.z, w0.w, w1.x, w1.y, w1.z, w1.w};
  u32 hb[8];
  #pragma unroll
  for (int i = 0; i < 8; ++i) hb[i] = f2bf(v[i] * rstd * wv[i]);
  uint4 up;
  up.x = hb[0] | (hb[1] << 16); up.y = hb[2] | (hb[3] << 16);
  up.z = hb[4] | (hb[5] << 16); up.w = hb[6] | (hb[7] << 16);
  *(uint4*)(out + off) = up;
}

// -- RMSNorm 2 + router (fp32 logits, exact argmax) + expert compaction --
__global__ __launch_bounds__(256)
void k_rmsnorm2_router(const float* __restrict__ xin, const float* __restrict__ w,
                       const float* __restrict__ rw, const float* __restrict__ rb,
                       u16* __restrict__ h2, int* __restrict__ cnt,
                       int* __restrict__ idx) {
  const int t = blockIdx.x, tid = threadIdx.x;
  const size_t off = (size_t)t * D_ + tid * 8;
  float4 x0 = *(const float4*)(xin + off);
  float4 x1 = *(const float4*)(xin + off + 4);
  float v[8] = {x0.x, x0.y, x0.z, x0.w, x1.x, x1.y, x1.z, x1.w};
  float ss = 0.f;
  #pragma unroll
  for (int i = 0; i < 8; ++i) ss += v[i] * v[i];
  #pragma unroll
  for (int o = 32; o > 0; o >>= 1) ss += __shfl_xor(ss, o, 64);
  __shared__ float red[4];
  __shared__ float rl[8];
  if ((tid & 63) == 0) red[tid >> 6] = ss;
  __syncthreads();
  const float tot = red[0] + red[1] + red[2] + red[3];
  const float rstd = 1.0f / sqrtf(tot / (float)D_ + 1e-6f);
  float4 w0 = *(const float4*)(w + tid * 8);
  float4 w1 = *(const float4*)(w + tid * 8 + 4);
  float wv[8] = {w0.x, w0.y, w0.z, w0.w, w1.x, w1.y, w1.z, w1.w};
  float4 ra = *(const float4*)(rw + tid * 8);
  float4 rb4 = *(const float4*)(rw + tid * 8 + 4);
  float4 rc = *(const float4*)(rw + D_ + tid * 8);
  float4 rd = *(const float4*)(rw + D_ + tid * 8 + 4);
  float r0[8] = {ra.x, ra.y, ra.z, ra.w, rb4.x, rb4.y, rb4.z, rb4.w};
  float r1[8] = {rc.x, rc.y, rc.z, rc.w, rd.x, rd.y, rd.z, rd.w};
  float l0 = 0.f, l1 = 0.f;
  u32 hb[8];
  #pragma unroll
  for (int i = 0; i < 8; ++i) {
    const float h = v[i] * rstd * wv[i];
    hb[i] = f2bf(h);
    l0 += h * r0[i];
    l1 += h * r1[i];
  }
  uint4 up;
  up.x = hb[0] | (hb[1] << 16); up.y = hb[2] | (hb[3] << 16);
  up.z = hb[4] | (hb[5] << 16); up.w = hb[6] | (hb[7] << 16);
  *(uint4*)(h2 + off) = up;
  #pragma unroll
  for (int o = 32; o > 0; o >>= 1) {
    l0 += __shfl_xor(l0, o, 64);
    l1 += __shfl_xor(l1, o, 64);
  }
  if ((tid & 63) == 0) { rl[tid >> 6] = l0; rl[4 + (tid >> 6)] = l1; }
  __syncthreads();
  if (tid == 0) {
    const float L0 = rl[0] + rl[1] + rl[2] + rl[3] + rb[0];
    const float L1 = rl[4] + rl[5] + rl[6] + rl[7] + rb[1];
    const int e = (L1 > L0) ? 1 : 0;   // tie -> 0, matches np argmax-first
    const int slot = atomicAdd(&cnt[e], 1);
    idx[e * MTOK + slot] = t;
  }
}

// ------- RoPE (fp64 trig): fp32 Q,K in -> bf16 out, Q scaled 1/sqrt(DH)
__global__ __launch_bounds__(256)
void k_rope_bf(const float* __restrict__ Q, const float* __restrict__ K,
               u16* __restrict__ Qo, u16* __restrict__ Ko) {
  const int t = blockIdx.x;
  const int s = t & (S_ - 1);
  const int d = threadIdx.x & 63;
  const int hq = threadIdx.x >> 6;
  const double inv = pow(10000.0, -(double)d / 64.0);
  const double ang = (double)s * inv;
  const float cf = (float)cos(ang);
  const float sf = (float)sin(ang);
  const float sc = 0.088388347648318447f;   // 1/sqrt(128) folded into Q
  #pragma unroll
  for (int i = 0; i < 4; ++i) {
    const int h = hq * 4 + i;
    const size_t idx = (size_t)t * D_ + h * DH_ + d;
    float x1 = Q[idx], x2 = Q[idx + 64];
    Qo[idx]      = f2bf((x1 * cf - x2 * sf) * sc);
    Qo[idx + 64] = f2bf((x2 * cf + x1 * sf) * sc);
    float y1 = K[idx], y2 = K[idx + 64];
    Ko[idx]      = f2bf(y1 * cf - y2 * sf);
    Ko[idx + 64] = f2bf(y2 * cf + y1 * sf);
  }
}

// ---------------- bf16 MFMA flash attention (causal) -------------------
// 4 waves/block; 64 q-rows/block (16 per wave); KV tile = 64.
// Q scaled by 1/sqrt(DH) already. Softmax fp32, P bf16, PV fp32 acc.
__global__ __launch_bounds__(256)
void k_attn_mfma(const u16* __restrict__ Qbf, const u16* __restrict__ Kbf,
                 const u16* __restrict__ Vbf, u16* __restrict__ O) {
  __shared__ u16 Ks[64 * 128];        // K tile, chunk-swizzled: p = (c&8)|((c&7)^(row&7))
  __shared__ u16 Vt[128 * 64];        // V^T tile, chunk-swz: p = c ^ (d&7) ^ ((d>>5)&3)
  __shared__ u16 Ps[4 * 16 * 64];     // per-wave P, chunk-swz: p = c ^ (q&7) ^ (q>>3)
  const int qx = blockIdx.x, h = blockIdx.y, b = blockIdx.z;
  const int qt = (qx & 1) ? (31 - (qx >> 1)) : (qx >> 1);   // pair long+short tiles
  const int tid = threadIdx.x;
  const int w = tid >> 6, lane = tid & 63;
  const int quad = lane >> 4, l16 = lane & 15;

  // Q fragments in registers (A operand rows = l16)
  const int q0 = qt * 64 + w * 16;
  const size_t qrow = (size_t)(b * S_ + q0 + l16) * D_ + h * DH_;
  bf16x8 qf[4];
  #pragma unroll
  for (int kd = 0; kd < 4; ++kd)
    qf[kd] = *(const bf16x8*)(Qbf + qrow + kd * 32 + quad * 8);

  f32x4 acc_o[8];
  #pragma unroll
  for (int i = 0; i < 8; ++i) acc_o[i] = 0;
  float mrun[4], lrun[4];
  #pragma unroll
  for (int r = 0; r < 4; ++r) { mrun[r] = -INFINITY; lrun[r] = 0.f; }

  const int nkt = qt + 1;
  const int vk = tid >> 2;              // V stage: this thread's kv row
  const int vd0 = (tid & 3) * 32;       // and d-range base

  for (int jt = 0; jt < nkt; ++jt) {
    const int kv0 = jt * 64;
    // --- stage K via global_load_lds, pre-swizzled source (rule 21) ---
    #pragma unroll
    for (int i = 0; i < 4; ++i) {
      const int slot = w * 256 + i * 64 + lane;
      const int r = slot >> 4, c = slot & 15;
      const int clog = (c & 8) | ((c & 7) ^ (r & 7));
      __builtin_amdgcn_global_load_lds(
        (const __attribute__((address_space(1))) void*)
          (Kbf + (size_t)(b * S_ + kv0 + r) * D_ + h * DH_ + clog * 8),
        (__attribute__((address_space(3))) void*)(Ks + (w * 256 + i * 64) * 8),
        16, 0, 0);
    }
    // --- stage V transposed (bf16 scatter, bank-swizzled) ---
    #pragma unroll
    for (int rr = 0; rr < 4; ++rr) {
      const int d0 = vd0 + rr * 8;
      bf16x8 vv = *(const bf16x8*)(Vbf + (size_t)(b * S_ + kv0 + vk) * D_ + h * DH_ + d0);
      const u16* pv = (const u16*)&vv;
      #pragma unroll
      for (int e = 0; e < 8; ++e) {
        const int d = d0 + e;
        Vt[d * 64 + ((((vk >> 3) ^ (d & 7) ^ ((d >> 5) & 3)) & 7) << 3) + (vk & 7)] = pv[e];
      }
    }
    __syncthreads();

    // --- QK^T: S[16q][64kv] per wave ---
    f32x4 st[4];
    #pragma unroll
    for (int nt = 0; nt < 4; ++nt) st[nt] = 0;
    #pragma unroll
    for (int kd = 0; kd < 4; ++kd) {
      #pragma unroll
      for (int nt = 0; nt < 4; ++nt) {
        const int kvr = nt * 16 + l16;
        const int c = kd * 4 + quad;
        const int p = (c & 8) | ((c & 7) ^ (kvr & 7));
        bf16x8 kf = *(const bf16x8*)(Ks + kvr * 128 + p * 8);
        st[nt] = __builtin_amdgcn_mfma_f32_16x16x32_bf16(qf[kd], kf, st[nt], 0, 0, 0);
      }
    }
    // --- causal mask (diagonal tile only) ---
    if (jt == qt) {
      #pragma unroll
      for (int nt = 0; nt < 4; ++nt) {
        const int kv = kv0 + nt * 16 + l16;
        #pragma unroll
        for (int r = 0; r < 4; ++r) {
          const int q = qt * 64 + w * 16 + quad * 4 + r;
          if (kv > q) st[nt][r] = -INFINITY;
        }
      }
    }
    // --- online softmax: rows = quad*4+r, reduce over l16 lanes ---
    float mx[4];
    #pragma unroll
    for (int r = 0; r < 4; ++r)
      mx[r] = fmaxf(fmaxf(st[0][r], st[1][r]), fmaxf(st[2][r], st[3][r]));
    #pragma unroll
    for (int o = 1; o < 16; o <<= 1) {
      #pragma unroll
      for (int r = 0; r < 4; ++r) mx[r] = fmaxf(mx[r], __shfl_xor(mx[r], o, 64));
    }
    float alpha[4], psum[4];
    #pragma unroll
    for (int r = 0; r < 4; ++r) {
      const float mnew = fmaxf(mrun[r], mx[r]);
      alpha[r] = expf(mrun[r] - mnew);
      mrun[r] = mnew;
      psum[r] = 0.f;
    }
    u16 pb[4][4];
    #pragma unroll
    for (int nt = 0; nt < 4; ++nt) {
      #pragma unroll
      for (int r = 0; r < 4; ++r) {
        const float p = expf(st[nt][r] - mrun[r]);
        psum[r] += p;
        pb[nt][r] = f2bf(p);
      }
    }
    #pragma unroll
    for (int o = 1; o < 16; o <<= 1) {
      #pragma unroll
      for (int r = 0; r < 4; ++r) psum[r] += __shfl_xor(psum[r], o, 64);
    }
    #pragma unroll
    for (int r = 0; r < 4; ++r) lrun[r] = lrun[r] * alpha[r] + psum[r];
    #pragma unroll
    for (int i = 0; i < 8; ++i) {
      #pragma unroll
      for (int r = 0; r < 4; ++r) acc_o[i][r] *= alpha[r];
    }
    // --- write P to per-wave private LDS region (no cross-wave sync) ---
    const int wbase = w * 1024;
    #pragma unroll
    for (int nt = 0; nt < 4; ++nt) {
      #pragma unroll
      for (int r = 0; r < 4; ++r) {
        const int q = quad * 4 + r;
        const int cc = ((nt * 2 + (l16 >> 3)) ^ (q & 7) ^ (q >> 3)) & 7;
        Ps[wbase + q * 64 + cc * 8 + (l16 & 7)] = pb[nt][r];
      }
    }
    // --- PV: O[16q][128d] += P[16q][64kv] * V[64kv][128d] ---
    #pragma unroll
    for (int ks = 0; ks < 2; ++ks) {
      const int cP = ((ks * 4 + quad) ^ (l16 & 7) ^ (l16 >> 3)) & 7;
      bf16x8 pa = *(const bf16x8*)(Ps + wbase + l16 * 64 + cP * 8);
      #pragma unroll
      for (int nt = 0; nt < 8; ++nt) {
        const int d = nt * 16 + l16;
        const int cV = ((ks * 4 + quad) ^ (d & 7) ^ ((d >> 5) & 3)) & 7;
        bf16x8 vf = *(const bf16x8*)(Vt + d * 64 + cV * 8);
        acc_o[nt] = __builtin_amdgcn_mfma_f32_16x16x32_bf16(pa, vf, acc_o[nt], 0, 0, 0);
      }
    }
    __syncthreads();
  }
  // --- epilogue: normalize, write bf16 ctx ---
  float invl[4];
  #pragma unroll
  for (int r = 0; r < 4; ++r) invl[r] = 1.0f / lrun[r];
  #pragma unroll
  for (int r = 0; r < 4; ++r) {
    const size_t orow = (size_t)(b * S_ + qt * 64 + w * 16 + quad * 4 + r) * D_ + h * DH_;
    #pragma unroll
    for (int nt = 0; nt < 8; ++nt)
      O[orow + nt * 16 + l16] = f2bf(acc_o[nt][r] * invl[r]);
  }
}

// ------- bf16 MFMA GEMM, C = A[M,K] * W[N,K]^T (+epilogue) -------------
// EPI 0: C(f32)[idx] = acc + bias[col]      (Q,K projections)
// EPI 1: C(f32)[idx] = acc + resf[idx]      (wo + residual)
// EPI 2: C(bf16)[idx] = acc + bias[col]     (V projection, direct bf16)
template<int EPI>
__global__ __launch_bounds__(256)
void k_lin_bf16(const u16* __restrict__ A, const u16* __restrict__ W,
                const float* __restrict__ bias, const float* __restrict__ resf,
                void* Cv, int N, int K) {
  __shared__ u16 As[128 * 32];
  __shared__ u16 Bs[128 * 32];
  const int tid = threadIdx.x;
  const int wave = tid >> 6, lane = tid & 63;
  const int quad = lane >> 4, l16 = lane & 15;
  const int m0 = blockIdx.y * 128, n0 = blockIdx.x * 128;
  const int wm = (wave >> 1) * 64, wn = (wave & 1) * 64;
  f32x4 acc[4][4];
  #pragma unroll
  for (int i = 0; i < 4; ++i)
    #pragma unroll
    for (int j = 0; j < 4; ++j) acc[i][j] = 0;

  for (int k0 = 0; k0 < K; k0 += 32) {
    #pragma unroll
    for (int c = 0; c < 2; ++c) {
      const int ci = (c * 4 + wave) * 64 + lane;
      const int row = ci >> 2, ko = (ci & 3) << 3;
      __builtin_amdgcn_global_load_lds(
          (const __attribute__((address_space(1))) void*)(A + (size_t)(m0 + row) * K + k0 + ko),
          (__attribute__((address_space(3))) void*)(As + (size_t)(c * 4 + wave) * 512),
          16, 0, 0);
      __builtin_amdgcn_global_load_lds(
          (const __attribute__((address_space(1))) void*)(W + (size_t)(n0 + row) * K + k0 + ko),
          (__attribute__((address_space(3))) void*)(Bs + (size_t)(c * 4 + wave) * 512),
          16, 0, 0);
    }
    __syncthreads();
    bf16x8 af[4], bfr[4];
    #pragma unroll
    for (int i = 0; i < 4; ++i)
      af[i] = *(const bf16x8*)(As + (wm + i * 16 + l16) * 32 + quad * 8);
    #pragma unroll
    for (int j = 0; j < 4; ++j)
      bfr[j] = *(const bf16x8*)(Bs + (wn + j * 16 + l16) * 32 + quad * 8);
    #pragma unroll
    for (int i = 0; i < 4; ++i)
      #pragma unroll
      for (int j = 0; j < 4; ++j)
        acc[i][j] = __builtin_amdgcn_mfma_f32_16x16x32_bf16(af[i], bfr[j], acc[i][j], 0, 0, 0);
    __syncthreads();
  }

  #pragma unroll
  for (int i = 0; i < 4; ++i) {
    #pragma unroll
    for (int r = 0; r < 4; ++r) {
      const int row = m0 + wm + i * 16 + quad * 4 + r;
      #pragma unroll
      for (int j = 0; j < 4; ++j) {
        const int col = n0 + wn + j * 16 + l16;
        const float v = acc[i][j][r];
        const size_t idx = (size_t)row * N + col;
        if (EPI == 0) {
          ((float*)Cv)[idx] = v + bias[col];
        } else if (EPI == 1) {
          ((float*)Cv)[idx] = v + resf[idx];
        } else {
          ((u16*)Cv)[idx] = f2bf(v + bias[col]);
        }
      }
    }
  }
}

// --- MoE gate/up GEMM with token gather on A, early-exit on count ------
// EPI 0: act(bf16)[row*N+col] = silu(acc)
// EPI 1: act(bf16)[row*N+col] = acc * gbuf[row*N+col]
template<int EPI>
__global__ __launch_bounds__(256)
void k_moe_gup(const u16* __restrict__ A, const u16* __restrict__ W,
               const u16* __restrict__ gbuf, const int* __restrict__ idx,
               const int* __restrict__ cnt, u16* __restrict__ Cb, int N, int K) {
  const int m0 = blockIdx.y * 128;
  const int cn = *cnt;
  if (m0 >= cn) return;
  __shared__ u16 As[128 * 32];
  __shared__ u16 Bs[128 * 32];
  const int tid = threadIdx.x;
  const int wave = tid >> 6, lane = tid & 63;
  const int quad = lane >> 4, l16 = lane & 15;
  const int n0 = blockIdx.x * 128;
  const int wm = (wave >> 1) * 64, wn = (wave & 1) * 64;
  f32x4 acc[4][4];
  #pragma unroll
  for (int i = 0; i < 4; ++i)
    #pragma unroll
    for (int j = 0; j < 4; ++j) acc[i][j] = 0;

  // gather: token index per staging row (fixed per thread across K)
  int tokc[2], koc[2], wrow[2];
  #pragma unroll
  for (int c = 0; c < 2; ++c) {
    const int ci = (c * 4 + wave) * 64 + lane;
    const int row = ci >> 2;
    tokc[c] = idx[m0 + row];
    wrow[c] = row;
    koc[c] = (ci & 3) << 3;
  }

  for (int k0 = 0; k0 < K; k0 += 32) {
    #pragma unroll
    for (int c = 0; c < 2; ++c) {
      __builtin_amdgcn_global_load_lds(
          (const __attribute__((address_space(1))) void*)(A + (size_t)tokc[c] * K + k0 + koc[c]),
          (__attribute__((address_space(3))) void*)(As + (size_t)(c * 4 + wave) * 512),
          16, 0, 0);
      __builtin_amdgcn_global_load_lds(
          (const __attribute__((address_space(1))) void*)(W + (size_t)(n0 + wrow[c]) * K + k0 + koc[c]),
          (__attribute__((address_space(3))) void*)(Bs + (size_t)(c * 4 + wave) * 512),
          16, 0, 0);
    }
    __syncthreads();
    bf16x8 af[4], bfr[4];
    #pragma unroll
    for (int i = 0; i < 4; ++i)
      af[i] = *(const bf16x8*)(As + (wm + i * 16 + l16) * 32 + quad * 8);
    #pragma unroll
    for (int j = 0; j < 4; ++j)
      bfr[j] = *(const bf16x8*)(Bs + (wn + j * 16 + l16) * 32 + quad * 8);
    #pragma unroll
    for (int i = 0; i < 4; ++i)
      #pragma unroll
      for (int j = 0; j < 4; ++j)
        acc[i][j] = __builtin_amdgcn_mfma_f32_16x16x32_bf16(af[i], bfr[j], acc[i][j], 0, 0, 0);
    __syncthreads();
  }

  #pragma unroll
  for (int i = 0; i < 4; ++i) {
    #pragma unroll
    for (int r = 0; r < 4; ++r) {
      const int row = m0 + wm + i * 16 + quad * 4 + r;
      #pragma unroll
      for (int j = 0; j < 4; ++j) {
        const int col = n0 + wn + j * 16 + l16;
        const float v = acc[i][j][r];
        const size_t oidx = (size_t)row * N + col;
        if (EPI == 0) {
          Cb[oidx] = f2bf(v / (1.0f + expf(-v)));
        } else {
          Cb[oidx] = f2bf(v * bf2f(gbuf[oidx]));
        }
      }
    }
  }
}

// --- MoE down GEMM: compact A, scatter out[tok] = res2[tok] + acc ------
__global__ __launch_bounds__(256)
void k_moe_down(const u16* __restrict__ A, const u16* __restrict__ W,
                const float* __restrict__ resf, const int* __restrict__ idx,
                const int* __restrict__ cnt, float* __restrict__ C, int N, int K) {
  const int m0 = blockIdx.y * 128;
  const int cn = *cnt;
  if (m0 >= cn) return;
  __shared__ u16 As[128 * 32];
  __shared__ u16 Bs[128 * 32];
  const int tid = threadIdx.x;
  const int wave = tid >> 6, lane = tid & 63;
  const int quad = lane >> 4, l16 = lane & 15;
  const int n0 = blockIdx.x * 128;
  const int wm = (wave >> 1) * 64, wn = (wave & 1) * 64;
  f32x4 acc[4][4];
  #pragma unroll
  for (int i = 0; i < 4; ++i)
    #pragma unroll
    for (int j = 0; j < 4; ++j) acc[i][j] = 0;

  for (int k0 = 0; k0 < K; k0 += 32) {
    #pragma unroll
    for (int c = 0; c < 2; ++c) {
      const int ci = (c * 4 + wave) * 64 + lane;
      const int row = ci >> 2, ko = (ci & 3) << 3;
      __builtin_amdgcn_global_load_lds(
          (const __attribute__((address_space(1))) void*)(A + (size_t)(m0 + row) * K + k0 + ko),
          (__attribute__((address_space(3))) void*)(As + (size_t)(c * 4 + wave) * 512),
          16, 0, 0);
      __builtin_amdgcn_global_load_lds(
          (const __attribute__((address_space(1))) void*)(W + (size_t)(n0 + row) * K + k0 + ko),
          (__attribute__((address_space(3))) void*)(Bs + (size_t)(c * 4 + wave) * 512),
          16, 0, 0);
    }
    __syncthreads();
    bf16x8 af[4], bfr[4];
    #pragma unroll
    for (int i = 0; i < 4; ++i)
      af[i] = *(const bf16x8*)(As + (wm + i * 16 + l16) * 32 + quad * 8);
    #pragma unroll
    for (int j = 0; j < 4; ++j)
      bfr[j] = *(const bf16x8*)(Bs + (wn + j * 16 + l16) * 32 + quad * 8);
    #pragma unroll
    for (int i = 0; i < 4; ++i)
      #pragma unroll
      for (int j = 0; j < 4; ++j)
        acc[i][j] = __builtin_amdgcn_mfma_f32_16x16x32_bf16(af[i], bfr[j], acc[i][j], 0, 0, 0);
    __syncthreads();
  }

  #pragma unroll
  for (int i = 0; i < 4; ++i) {
    #pragma unroll
    for (int r = 0; r < 4; ++r) {
      const int row = m0 + wm + i * 16 + quad * 4 + r;
      if (row < cn) {
        const int tok = idx[row];
        #pragma unroll
        for (int j = 0; j < 4; ++j) {
          const int col = n0 + wn + j * 16 + l16;
          const size_t oidx = (size_t)tok * N + col;
          C[oidx] = resf[oidx] + acc[i][j][r];
        }
      }
    }
  }
}

// ---------------- launcher --------------------------------------------
extern "C" void kernel_launch(void* const* d_in, const int* in_sizes, int n_in,
                              void* d_out, int out_size, void* d_ws, size_t ws_size,
                              hipStream_t stream) {
  (void)in_sizes; (void)n_in; (void)out_size; (void)ws_size;
  const float* hidden = (const float*)d_in[0];
  const float* ln1w   = (const float*)d_in[1];
  const float* wq     = (const float*)d_in[2];
  const float* bq     = (const float*)d_in[3];
  const float* wk     = (const float*)d_in[4];
  const float* bk     = (const float*)d_in[5];
  const float* wv     = (const float*)d_in[6];
  const float* bv     = (const float*)d_in[7];
  const float* wo     = (const float*)d_in[8];
  const float* ln2w   = (const float*)d_in[9];
  const float* e1g    = (const float*)d_in[10];
  const float* e1u    = (const float*)d_in[11];
  const float* e1d    = (const float*)d_in[12];
  const float* e2g    = (const float*)d_in[13];
  const float* e2u    = (const float*)d_in[14];
  const float* e2d    = (const float*)d_in[15];
  const float* rw     = (const float*)d_in[16];
  const float* rb     = (const float*)d_in[17];
  float* out = (float*)d_out;
  char* ws = (char*)d_ws;

  const size_t MB = 1024 * 1024;
  // layout (MiB):
  // [0,16)    h1b bf16
  // [16,48)   Qb f32            -> res2 f32 after attention
  // [48,80)   Kb f32            -> h2b bf16 [48,64) after attn
  // [80,96)   Qbf bf16          -> act bf16 [80,123) after attn
  // [96,112)  Kbf bf16              (same act region)
  // [112,128) Vbf bf16              (same act region)
  // [128,144) ctxb bf16         -> idx/cnt (dead after wo gemm; zeroed AFTER it)
  // [144,152) wlin bf16 (DxD, reused 4x) -> wbf bf16 [144,166) (MoE, reused 6x)
  u16*   h1b  = (u16*)(ws);
  float* Qb   = (float*)(ws + 16 * MB);
  float* Kb   = (float*)(ws + 48 * MB);
  u16*   Qbf  = (u16*)(ws + 80 * MB);
  u16*   Kbf  = (u16*)(ws + 96 * MB);
  u16*   Vbf  = (u16*)(ws + 112 * MB);
  u16*   ctxb = (u16*)(ws + 128 * MB);
  float* res2 = Qb;
  u16*   h2b  = (u16*)(ws + 48 * MB);
  int*   idx  = (int*)(ws + 128 * MB);         // 2 x 4096 ints (ctxb region, dead)
  int*   cnt  = (int*)(ws + 128 * MB + 64 * 1024);
  u16*   act  = (u16*)(ws + 80 * MB);
  u16*   wlin = (u16*)(ws + 144 * MB);
  u16*   wbf  = (u16*)(ws + 144 * MB);

  k_rmsnorm1<<<MTOK, 256, 0, stream>>>(hidden, ln1w, h1b);

  const int WD = (D_ * D_) / 8 / 256;      // 2048 blocks per D x D weight
  const int WCONV = (F_ * D_) / 8 / 256;   // 5504 blocks per F x D weight
  dim3 gQKV(D_ / 128, MTOK / 128);

  k_f2bf<<<WD, 256, 0, stream>>>(wq, wlin);
  k_lin_bf16<0><<<gQKV, 256, 0, stream>>>(h1b, wlin, bq, nullptr, Qb, D_, D_);
  k_f2bf<<<WD, 256, 0, stream>>>(wk, wlin);
  k_lin_bf16<0><<<gQKV, 256, 0, stream>>>(h1b, wlin, bk, nullptr, Kb, D_, D_);
  k_f2bf<<<WD, 256, 0, stream>>>(wv, wlin);
  k_lin_bf16<2><<<gQKV, 256, 0, stream>>>(h1b, wlin, bv, nullptr, Vbf, D_, D_);

  k_rope_bf<<<MTOK, 256, 0, stream>>>(Qb, Kb, Qbf, Kbf);
  k_attn_mfma<<<dim3(32, NH_, 2), 256, 0, stream>>>(Qbf, Kbf, Vbf, ctxb);

  k_f2bf<<<WD, 256, 0, stream>>>(wo, wlin);
  k_lin_bf16<1><<<gQKV, 256, 0, stream>>>(ctxb, wlin, nullptr, hidden, res2, D_, D_);

  // ctxb region is dead from here; init routing state in it, then route
  k_moe_init<<<1, 256, 0, stream>>>(cnt, idx);
  k_rmsnorm2_router<<<MTOK, 256, 0, stream>>>(res2, ln2w, rw, rb, h2b, cnt, idx);

  dim3 gFU(F_ / 128, MTOK / 128), gDN(D_ / 128, MTOK / 128);

  // expert 1 (tokens with choice==0), routed
  k_f2bf<<<WCONV, 256, 0, stream>>>(e1g, wbf);
  k_moe_gup<0><<<gFU, 256, 0, stream>>>(h2b, wbf, nullptr, idx, cnt, act, F_, D_);
  k_f2bf<<<WCONV, 256, 0, stream>>>(e1u, wbf);
  k_moe_gup<1><<<gFU, 256, 0, stream>>>(h2b, wbf, act, idx, cnt, act, F_, D_);
  k_f2bf<<<WCONV, 256, 0, stream>>>(e1d, wbf);
  k_moe_down<<<gDN, 256, 0, stream>>>(act, wbf, res2, idx, cnt, out, D_, F_);
  // expert 2 (tokens with choice==1), routed
  k_f2bf<<<WCONV, 256, 0, stream>>>(e2g, wbf);
  k_moe_gup<0><<<gFU, 256, 0, stream>>>(h2b, wbf, nullptr, idx + MTOK, cnt + 1, act, F_, D_);
  k_f2bf<<<WCONV, 256, 0, stream>>>(e2u, wbf);
  k_moe_gup<1><<<gFU, 256, 0, stream>>>(h2b, wbf, act, idx + MTOK, cnt + 1, act, F_, D_);
  k_f2bf<<<WCONV, 256, 0, stream>>>(e2d, wbf);
  k_moe_down<<<gDN, 256, 0, stream>>>(act, wbf, res2, idx + MTOK, cnt + 1, out, D_, F_);
}

// Round 5
// 1567.580 us; speedup vs baseline: 2.5477x; 1.0718x over previous
//
#include <hip/hip_runtime.h>
#include <math.h>

typedef unsigned short u16;
typedef unsigned int u32;

#define D_ 2048
#define S_ 2048
#define DH_ 128
#define NH_ 16
#define F_ 5504
#define MTOK 4096

typedef __bf16 bf16x8 __attribute__((ext_vector_type(8)));
typedef float f32x4 __attribute__((ext_vector_type(4)));

__device__ __forceinline__ float bf2f(u32 u) {
  union { u32 i; float f; } x; x.i = u << 16; return x.f;
}
__device__ __forceinline__ u16 f2bf(float f) {
  u32 x = __float_as_uint(f);
  return (u16)((x + 0x7fffu + ((x >> 16) & 1u)) >> 16);
}

// ---------------- fp32 -> bf16 elementwise convert (weights) ----------
__global__ __launch_bounds__(256)
void k_f2bf(const float* __restrict__ src, u16* __restrict__ dst) {
  const size_t i = ((size_t)blockIdx.x * 256 + threadIdx.x) * 8;
  float4 a = *(const float4*)(src + i);
  float4 b = *(const float4*)(src + i + 4);
  uint4 p;
  p.x = f2bf(a.x) | ((u32)f2bf(a.y) << 16);
  p.y = f2bf(a.z) | ((u32)f2bf(a.w) << 16);
  p.z = f2bf(b.x) | ((u32)f2bf(b.y) << 16);
  p.w = f2bf(b.z) | ((u32)f2bf(b.w) << 16);
  *(uint4*)(dst + i) = p;
}

// ---------------- MoE routing init: zero counters + idx ----------------
__global__ __launch_bounds__(256)
void k_moe_init(int* __restrict__ cnt, int* __restrict__ idx) {
  const int tid = threadIdx.x;
  if (tid < 2) cnt[tid] = 0;
  for (int i = tid; i < 2 * MTOK; i += 256) idx[i] = 0;
}

// ---------------- RMSNorm 1: f32 in -> bf16 normed out ----------------
__global__ __launch_bounds__(256)
void k_rmsnorm1(const float* __restrict__ x, const float* __restrict__ w,
                u16* __restrict__ out) {
  const int t = blockIdx.x, tid = threadIdx.x;
  const size_t off = (size_t)t * D_ + tid * 8;
  float4 x0 = *(const float4*)(x + off);
  float4 x1 = *(const float4*)(x + off + 4);
  float v[8] = {x0.x, x0.y, x0.z, x0.w, x1.x, x1.y, x1.z, x1.w};
  float ss = 0.f;
  #pragma unroll
  for (int i = 0; i < 8; ++i) ss += v[i] * v[i];
  #pragma unroll
  for (int o = 32; o > 0; o >>= 1) ss += __shfl_xor(ss, o, 64);
  __shared__ float red[4];
  if ((tid & 63) == 0) red[tid >> 6] = ss;
  __syncthreads();
  const float tot = red[0] + red[1] + red[2] + red[3];
  const float rstd = 1.0f / sqrtf(tot / (float)D_ + 1e-6f);
  float4 w0 = *(const float4*)(w + tid * 8);
  float4 w1 = *(const float4*)(w + tid * 8 + 4);
  float wv[8] = {w0.x, w0.y, w0.z, w0.w, w1.x, w1.y, w1.z, w1.w};
  u32 hb[8];
  #pragma unroll
  for (int i = 0; i < 8; ++i) hb[i] = f2bf(v[i] * rstd * wv[i]);
  uint4 up;
  up.x = hb[0] | (hb[1] << 16); up.y = hb[2] | (hb[3] << 16);
  up.z = hb[4] | (hb[5] << 16); up.w = hb[6] | (hb[7] << 16);
  *(uint4*)(out + off) = up;
}

// -- RMSNorm 2 + router (fp32 logits, exact argmax) + expert compaction --
__global__ __launch_bounds__(256)
void k_rmsnorm2_router(const float* __restrict__ xin, const float* __restrict__ w,
                       const float* __restrict__ rw, const float* __restrict__ rb,
                       u16* __restrict__ h2, int* __restrict__ cnt,
                       int* __restrict__ idx) {
  const int t = blockIdx.x, tid = threadIdx.x;
  const size_t off = (size_t)t * D_ + tid * 8;
  float4 x0 = *(const float4*)(xin + off);
  float4 x1 = *(const float4*)(xin + off + 4);
  float v[8] = {x0.x, x0.y, x0.z, x0.w, x1.x, x1.y, x1.z, x1.w};
  float ss = 0.f;
  #pragma unroll
  for (int i = 0; i < 8; ++i) ss += v[i] * v[i];
  #pragma unroll
  for (int o = 32; o > 0; o >>= 1) ss += __shfl_xor(ss, o, 64);
  __shared__ float red[4];
  __shared__ float rl[8];
  if ((tid & 63) == 0) red[tid >> 6] = ss;
  __syncthreads();
  const float tot = red[0] + red[1] + red[2] + red[3];
  const float rstd = 1.0f / sqrtf(tot / (float)D_ + 1e-6f);
  float4 w0 = *(const float4*)(w + tid * 8);
  float4 w1 = *(const float4*)(w + tid * 8 + 4);
  float wv[8] = {w0.x, w0.y, w0.z, w0.w, w1.x, w1.y, w1.z, w1.w};
  float4 ra = *(const float4*)(rw + tid * 8);
  float4 rb4 = *(const float4*)(rw + tid * 8 + 4);
  float4 rc = *(const float4*)(rw + D_ + tid * 8);
  float4 rd = *(const float4*)(rw + D_ + tid * 8 + 4);
  float r0[8] = {ra.x, ra.y, ra.z, ra.w, rb4.x, rb4.y, rb4.z, rb4.w};
  float r1[8] = {rc.x, rc.y, rc.z, rc.w, rd.x, rd.y, rd.z, rd.w};
  float l0 = 0.f, l1 = 0.f;
  u32 hb[8];
  #pragma unroll
  for (int i = 0; i < 8; ++i) {
    const float h = v[i] * rstd * wv[i];
    hb[i] = f2bf(h);
    l0 += h * r0[i];
    l1 += h * r1[i];
  }
  uint4 up;
  up.x = hb[0] | (hb[1] << 16); up.y = hb[2] | (hb[3] << 16);
  up.z = hb[4] | (hb[5] << 16); up.w = hb[6] | (hb[7] << 16);
  *(uint4*)(h2 + off) = up;
  #pragma unroll
  for (int o = 32; o > 0; o >>= 1) {
    l0 += __shfl_xor(l0, o, 64);
    l1 += __shfl_xor(l1, o, 64);
  }
  if ((tid & 63) == 0) { rl[tid >> 6] = l0; rl[4 + (tid >> 6)] = l1; }
  __syncthreads();
  if (tid == 0) {
    const float L0 = rl[0] + rl[1] + rl[2] + rl[3] + rb[0];
    const float L1 = rl[4] + rl[5] + rl[6] + rl[7] + rb[1];
    const int e = (L1 > L0) ? 1 : 0;   // tie -> 0, matches np argmax-first
    const int slot = atomicAdd(&cnt[e], 1);
    idx[e * MTOK + slot] = t;
  }
}

// ------- RoPE (fp64 trig): fp32 Q,K in -> bf16 out, Q scaled 1/sqrt(DH)
__global__ __launch_bounds__(256)
void k_rope_bf(const float* __restrict__ Q, const float* __restrict__ K,
               u16* __restrict__ Qo, u16* __restrict__ Ko) {
  const int t = blockIdx.x;
  const int s = t & (S_ - 1);
  const int d = threadIdx.x & 63;
  const int hq = threadIdx.x >> 6;
  const double inv = pow(10000.0, -(double)d / 64.0);
  const double ang = (double)s * inv;
  const float cf = (float)cos(ang);
  const float sf = (float)sin(ang);
  const float sc = 0.088388347648318447f;   // 1/sqrt(128) folded into Q
  #pragma unroll
  for (int i = 0; i < 4; ++i) {
    const int h = hq * 4 + i;
    const size_t idx = (size_t)t * D_ + h * DH_ + d;
    float x1 = Q[idx], x2 = Q[idx + 64];
    Qo[idx]      = f2bf((x1 * cf - x2 * sf) * sc);
    Qo[idx + 64] = f2bf((x2 * cf + x1 * sf) * sc);
    float y1 = K[idx], y2 = K[idx + 64];
    Ko[idx]      = f2bf(y1 * cf - y2 * sf);
    Ko[idx + 64] = f2bf(y2 * cf + y1 * sf);
  }
}

// ---------------- bf16 MFMA flash attention (causal) -------------------
// 4 waves/block; 64 q-rows/block (16 per wave); KV tile = 64.
// Q scaled by 1/sqrt(DH) already. Softmax fp32, P bf16, PV fp32 acc.
// V comes pre-transposed: VT[b][h][d][s].
__global__ __launch_bounds__(256)
void k_attn_mfma(const u16* __restrict__ Qbf, const u16* __restrict__ Kbf,
                 const u16* __restrict__ VT, u16* __restrict__ O) {
  __shared__ u16 Ks[64 * 128];        // K tile, chunk-swz: p = (c&8)|((c&7)^(row&7))
  __shared__ u16 Vs[128 * 64];        // V^T tile [d][kv], chunk-swz: c ^ (d&7)
  __shared__ u16 Ps[4 * 16 * 64];     // per-wave P, chunk-swz: p = c ^ (q&7) ^ (q>>3)
  const int qx = blockIdx.x, h = blockIdx.y, b = blockIdx.z;
  const int qt = (qx & 1) ? (31 - (qx >> 1)) : (qx >> 1);   // pair long+short tiles
  const int tid = threadIdx.x;
  const int w = tid >> 6, lane = tid & 63;
  const int quad = lane >> 4, l16 = lane & 15;

  // Q fragments in registers (A operand rows = l16)
  const int q0 = qt * 64 + w * 16;
  const size_t qrow = (size_t)(b * S_ + q0 + l16) * D_ + h * DH_;
  bf16x8 qf[4];
  #pragma unroll
  for (int kd = 0; kd < 4; ++kd)
    qf[kd] = *(const bf16x8*)(Qbf + qrow + kd * 32 + quad * 8);

  f32x4 acc_o[8];
  #pragma unroll
  for (int i = 0; i < 8; ++i) acc_o[i] = 0;
  float mrun[4], lrun[4];
  #pragma unroll
  for (int r = 0; r < 4; ++r) { mrun[r] = -INFINITY; lrun[r] = 0.f; }

  // hoisted jt-invariant staging offsets
  const u16* vtbase = VT + (size_t)(b * NH_ + h) * DH_ * S_;
  const u16* kbase  = Kbf + (size_t)(b) * S_ * D_ + h * DH_;
  int krow[4], kcol[4], vrow[4], vcol[4];
  #pragma unroll
  for (int i = 0; i < 4; ++i) {
    const int slot = w * 256 + i * 64 + lane;
    const int kr = slot >> 4, kc = slot & 15;
    krow[i] = kr;
    kcol[i] = ((kc & 8) | ((kc & 7) ^ (kr & 7))) * 8;
    const int vr = slot >> 3, vc = slot & 7;
    vrow[i] = vr;
    vcol[i] = (vc ^ (vr & 7)) * 8;
  }

  const int nkt = qt + 1;
  for (int jt = 0; jt < nkt; ++jt) {
    const int kv0 = jt * 64;
    // --- stage K + V^T via global_load_lds, pre-swizzled sources ---
    #pragma unroll
    for (int i = 0; i < 4; ++i) {
      __builtin_amdgcn_global_load_lds(
        (const __attribute__((address_space(1))) void*)
          (kbase + (size_t)(kv0 + krow[i]) * D_ + kcol[i]),
        (__attribute__((address_space(3))) void*)(Ks + (w * 256 + i * 64) * 8),
        16, 0, 0);
      __builtin_amdgcn_global_load_lds(
        (const __attribute__((address_space(1))) void*)
          (vtbase + (size_t)vrow[i] * S_ + kv0 + vcol[i]),
        (__attribute__((address_space(3))) void*)(Vs + (w * 256 + i * 64) * 8),
        16, 0, 0);
    }
    __syncthreads();

    // --- QK^T: S[16q][64kv] per wave ---
    f32x4 st[4];
    #pragma unroll
    for (int nt = 0; nt < 4; ++nt) st[nt] = 0;
    __builtin_amdgcn_s_setprio(1);
    #pragma unroll
    for (int kd = 0; kd < 4; ++kd) {
      #pragma unroll
      for (int nt = 0; nt < 4; ++nt) {
        const int kvr = nt * 16 + l16;
        const int c = kd * 4 + quad;
        const int p = (c & 8) | ((c & 7) ^ (kvr & 7));
        bf16x8 kf = *(const bf16x8*)(Ks + kvr * 128 + p * 8);
        st[nt] = __builtin_amdgcn_mfma_f32_16x16x32_bf16(qf[kd], kf, st[nt], 0, 0, 0);
      }
    }
    __builtin_amdgcn_s_setprio(0);
    // --- causal mask (diagonal tile only) ---
    if (jt == qt) {
      #pragma unroll
      for (int nt = 0; nt < 4; ++nt) {
        const int kv = kv0 + nt * 16 + l16;
        #pragma unroll
        for (int r = 0; r < 4; ++r) {
          const int q = qt * 64 + w * 16 + quad * 4 + r;
          if (kv > q) st[nt][r] = -INFINITY;
        }
      }
    }
    // --- online softmax: rows = quad*4+r, reduce over l16 lanes ---
    float mx[4];
    #pragma unroll
    for (int r = 0; r < 4; ++r)
      mx[r] = fmaxf(fmaxf(st[0][r], st[1][r]), fmaxf(st[2][r], st[3][r]));
    #pragma unroll
    for (int o = 1; o < 16; o <<= 1) {
      #pragma unroll
      for (int r = 0; r < 4; ++r) mx[r] = fmaxf(mx[r], __shfl_xor(mx[r], o, 64));
    }
    float alpha[4], psum[4];
    #pragma unroll
    for (int r = 0; r < 4; ++r) {
      const float mnew = fmaxf(mrun[r], mx[r]);
      alpha[r] = expf(mrun[r] - mnew);
      mrun[r] = mnew;
      psum[r] = 0.f;
    }
    u16 pb[4][4];
    #pragma unroll
    for (int nt = 0; nt < 4; ++nt) {
      #pragma unroll
      for (int r = 0; r < 4; ++r) {
        const float p = expf(st[nt][r] - mrun[r]);
        psum[r] += p;
        pb[nt][r] = f2bf(p);
      }
    }
    #pragma unroll
    for (int o = 1; o < 16; o <<= 1) {
      #pragma unroll
      for (int r = 0; r < 4; ++r) psum[r] += __shfl_xor(psum[r], o, 64);
    }
    #pragma unroll
    for (int r = 0; r < 4; ++r) lrun[r] = lrun[r] * alpha[r] + psum[r];
    #pragma unroll
    for (int i = 0; i < 8; ++i) {
      #pragma unroll
      for (int r = 0; r < 4; ++r) acc_o[i][r] *= alpha[r];
    }
    // --- write P to per-wave private LDS region (no cross-wave sync) ---
    const int wbase = w * 1024;
    #pragma unroll
    for (int nt = 0; nt < 4; ++nt) {
      #pragma unroll
      for (int r = 0; r < 4; ++r) {
        const int q = quad * 4 + r;
        const int cc = ((nt * 2 + (l16 >> 3)) ^ (q & 7) ^ (q >> 3)) & 7;
        Ps[wbase + q * 64 + cc * 8 + (l16 & 7)] = pb[nt][r];
      }
    }
    // --- PV: O[16q][128d] += P[16q][64kv] * V[64kv][128d] ---
    __builtin_amdgcn_s_setprio(1);
    #pragma unroll
    for (int ks = 0; ks < 2; ++ks) {
      const int cP = ((ks * 4 + quad) ^ (l16 & 7) ^ (l16 >> 3)) & 7;
      bf16x8 pa = *(const bf16x8*)(Ps + wbase + l16 * 64 + cP * 8);
      #pragma unroll
      for (int nt = 0; nt < 8; ++nt) {
        const int d = nt * 16 + l16;
        const int cV = ((ks * 4 + quad) ^ (d & 7)) & 7;
        bf16x8 vf = *(const bf16x8*)(Vs + d * 64 + cV * 8);
        acc_o[nt] = __builtin_amdgcn_mfma_f32_16x16x32_bf16(pa, vf, acc_o[nt], 0, 0, 0);
      }
    }
    __builtin_amdgcn_s_setprio(0);
    __syncthreads();
  }
  // --- epilogue: normalize, write bf16 ctx ---
  float invl[4];
  #pragma unroll
  for (int r = 0; r < 4; ++r) invl[r] = 1.0f / lrun[r];
  #pragma unroll
  for (int r = 0; r < 4; ++r) {
    const size_t orow = (size_t)(b * S_ + qt * 64 + w * 16 + quad * 4 + r) * D_ + h * DH_;
    #pragma unroll
    for (int nt = 0; nt < 8; ++nt)
      O[orow + nt * 16 + l16] = f2bf(acc_o[nt][r] * invl[r]);
  }
}

// ------- bf16 MFMA GEMM, C = A[M,K] * W[N,K]^T (+epilogue) -------------
// EPI 0: C(f32)[idx] = acc + bias[col]      (Q,K projections)
// EPI 1: C(f32)[idx] = acc + resf[idx]      (wo + residual)
// EPI 3: V^T write:  VT[((b*NH+h)*DH+d)*S + s] = bf16(acc + bias[col])
template<int EPI>
__global__ __launch_bounds__(256)
void k_lin_bf16(const u16* __restrict__ A, const u16* __restrict__ W,
                const float* __restrict__ bias, const float* __restrict__ resf,
                void* Cv, int N, int K) {
  __shared__ u16 As[128 * 32];
  __shared__ u16 Bs[128 * 32];
  const int tid = threadIdx.x;
  const int wave = tid >> 6, lane = tid & 63;
  const int quad = lane >> 4, l16 = lane & 15;
  const int m0 = blockIdx.y * 128, n0 = blockIdx.x * 128;
  const int wm = (wave >> 1) * 64, wn = (wave & 1) * 64;
  f32x4 acc[4][4];
  #pragma unroll
  for (int i = 0; i < 4; ++i)
    #pragma unroll
    for (int j = 0; j < 4; ++j) acc[i][j] = 0;

  for (int k0 = 0; k0 < K; k0 += 32) {
    #pragma unroll
    for (int c = 0; c < 2; ++c) {
      const int ci = (c * 4 + wave) * 64 + lane;
      const int row = ci >> 2, ko = (ci & 3) << 3;
      __builtin_amdgcn_global_load_lds(
          (const __attribute__((address_space(1))) void*)(A + (size_t)(m0 + row) * K + k0 + ko),
          (__attribute__((address_space(3))) void*)(As + (size_t)(c * 4 + wave) * 512),
          16, 0, 0);
      __builtin_amdgcn_global_load_lds(
          (const __attribute__((address_space(1))) void*)(W + (size_t)(n0 + row) * K + k0 + ko),
          (__attribute__((address_space(3))) void*)(Bs + (size_t)(c * 4 + wave) * 512),
          16, 0, 0);
    }
    __syncthreads();
    bf16x8 af[4], bfr[4];
    #pragma unroll
    for (int i = 0; i < 4; ++i)
      af[i] = *(const bf16x8*)(As + (wm + i * 16 + l16) * 32 + quad * 8);
    #pragma unroll
    for (int j = 0; j < 4; ++j)
      bfr[j] = *(const bf16x8*)(Bs + (wn + j * 16 + l16) * 32 + quad * 8);
    #pragma unroll
    for (int i = 0; i < 4; ++i)
      #pragma unroll
      for (int j = 0; j < 4; ++j)
        acc[i][j] = __builtin_amdgcn_mfma_f32_16x16x32_bf16(af[i], bfr[j], acc[i][j], 0, 0, 0);
    __syncthreads();
  }

  if (EPI == 3) {
    // V^T epilogue: pack 4 consecutive s (r=0..3) as ushort4
    u16* vt = (u16*)Cv;
    #pragma unroll
    for (int i = 0; i < 4; ++i) {
      const int row0 = m0 + wm + i * 16 + quad * 4;
      const int bb = row0 >> 11, s0 = row0 & (S_ - 1);
      #pragma unroll
      for (int j = 0; j < 4; ++j) {
        const int col = n0 + wn + j * 16 + l16;
        const float bv = bias[col];
        ushort4 p;
        p.x = f2bf(acc[i][j][0] + bv);
        p.y = f2bf(acc[i][j][1] + bv);
        p.z = f2bf(acc[i][j][2] + bv);
        p.w = f2bf(acc[i][j][3] + bv);
        const size_t vtr = (size_t)((bb * NH_ + (col >> 7)) * DH_ + (col & (DH_ - 1)));
        *(ushort4*)(vt + vtr * S_ + s0) = p;
      }
    }
    return;
  }

  #pragma unroll
  for (int i = 0; i < 4; ++i) {
    #pragma unroll
    for (int r = 0; r < 4; ++r) {
      const int row = m0 + wm + i * 16 + quad * 4 + r;
      #pragma unroll
      for (int j = 0; j < 4; ++j) {
        const int col = n0 + wn + j * 16 + l16;
        const float v = acc[i][j][r];
        const size_t idx = (size_t)row * N + col;
        if (EPI == 0) {
          ((float*)Cv)[idx] = v + bias[col];
        } else if (EPI == 1) {
          ((float*)Cv)[idx] = v + resf[idx];
        }
      }
    }
  }
}

// --- MoE gate/up GEMM with token gather on A, early-exit on count ------
// EPI 0: act(bf16)[row*N+col] = silu(acc)
// EPI 1: act(bf16)[row*N+col] = acc * gbuf[row*N+col]
template<int EPI>
__global__ __launch_bounds__(256)
void k_moe_gup(const u16* __restrict__ A, const u16* __restrict__ W,
               const u16* __restrict__ gbuf, const int* __restrict__ idx,
               const int* __restrict__ cnt, u16* __restrict__ Cb, int N, int K) {
  const int m0 = blockIdx.y * 128;
  const int cn = *cnt;
  if (m0 >= cn) return;
  __shared__ u16 As[128 * 32];
  __shared__ u16 Bs[128 * 32];
  const int tid = threadIdx.x;
  const int wave = tid >> 6, lane = tid & 63;
  const int quad = lane >> 4, l16 = lane & 15;
  const int n0 = blockIdx.x * 128;
  const int wm = (wave >> 1) * 64, wn = (wave & 1) * 64;
  f32x4 acc[4][4];
  #pragma unroll
  for (int i = 0; i < 4; ++i)
    #pragma unroll
    for (int j = 0; j < 4; ++j) acc[i][j] = 0;

  // gather: token index per staging row (fixed per thread across K)
  int tokc[2], koc[2], wrow[2];
  #pragma unroll
  for (int c = 0; c < 2; ++c) {
    const int ci = (c * 4 + wave) * 64 + lane;
    const int row = ci >> 2;
    tokc[c] = idx[m0 + row];
    wrow[c] = row;
    koc[c] = (ci & 3) << 3;
  }

  for (int k0 = 0; k0 < K; k0 += 32) {
    #pragma unroll
    for (int c = 0; c < 2; ++c) {
      __builtin_amdgcn_global_load_lds(
          (const __attribute__((address_space(1))) void*)(A + (size_t)tokc[c] * K + k0 + koc[c]),
          (__attribute__((address_space(3))) void*)(As + (size_t)(c * 4 + wave) * 512),
          16, 0, 0);
      __builtin_amdgcn_global_load_lds(
          (const __attribute__((address_space(1))) void*)(W + (size_t)(n0 + wrow[c]) * K + k0 + koc[c]),
          (__attribute__((address_space(3))) void*)(Bs + (size_t)(c * 4 + wave) * 512),
          16, 0, 0);
    }
    __syncthreads();
    bf16x8 af[4], bfr[4];
    #pragma unroll
    for (int i = 0; i < 4; ++i)
      af[i] = *(const bf16x8*)(As + (wm + i * 16 + l16) * 32 + quad * 8);
    #pragma unroll
    for (int j = 0; j < 4; ++j)
      bfr[j] = *(const bf16x8*)(Bs + (wn + j * 16 + l16) * 32 + quad * 8);
    #pragma unroll
    for (int i = 0; i < 4; ++i)
      #pragma unroll
      for (int j = 0; j < 4; ++j)
        acc[i][j] = __builtin_amdgcn_mfma_f32_16x16x32_bf16(af[i], bfr[j], acc[i][j], 0, 0, 0);
    __syncthreads();
  }

  #pragma unroll
  for (int i = 0; i < 4; ++i) {
    #pragma unroll
    for (int r = 0; r < 4; ++r) {
      const int row = m0 + wm + i * 16 + quad * 4 + r;
      #pragma unroll
      for (int j = 0; j < 4; ++j) {
        const int col = n0 + wn + j * 16 + l16;
        const float v = acc[i][j][r];
        const size_t oidx = (size_t)row * N + col;
        if (EPI == 0) {
          Cb[oidx] = f2bf(v / (1.0f + expf(-v)));
        } else {
          Cb[oidx] = f2bf(v * bf2f(gbuf[oidx]));
        }
      }
    }
  }
}

// --- MoE down GEMM: compact A, scatter out[tok] = res2[tok] + acc ------
__global__ __launch_bounds__(256)
void k_moe_down(const u16* __restrict__ A, const u16* __restrict__ W,
                const float* __restrict__ resf, const int* __restrict__ idx,
                const int* __restrict__ cnt, float* __restrict__ C, int N, int K) {
  const int m0 = blockIdx.y * 128;
  const int cn = *cnt;
  if (m0 >= cn) return;
  __shared__ u16 As[128 * 32];
  __shared__ u16 Bs[128 * 32];
  const int tid = threadIdx.x;
  const int wave = tid >> 6, lane = tid & 63;
  const int quad = lane >> 4, l16 = lane & 15;
  const int n0 = blockIdx.x * 128;
  const int wm = (wave >> 1) * 64, wn = (wave & 1) * 64;
  f32x4 acc[4][4];
  #pragma unroll
  for (int i = 0; i < 4; ++i)
    #pragma unroll
    for (int j = 0; j < 4; ++j) acc[i][j] = 0;

  for (int k0 = 0; k0 < K; k0 += 32) {
    #pragma unroll
    for (int c = 0; c < 2; ++c) {
      const int ci = (c * 4 + wave) * 64 + lane;
      const int row = ci >> 2, ko = (ci & 3) << 3;
      __builtin_amdgcn_global_load_lds(
          (const __attribute__((address_space(1))) void*)(A + (size_t)(m0 + row) * K + k0 + ko),
          (__attribute__((address_space(3))) void*)(As + (size_t)(c * 4 + wave) * 512),
          16, 0, 0);
      __builtin_amdgcn_global_load_lds(
          (const __attribute__((address_space(1))) void*)(W + (size_t)(n0 + row) * K + k0 + ko),
          (__attribute__((address_space(3))) void*)(Bs + (size_t)(c * 4 + wave) * 512),
          16, 0, 0);
    }
    __syncthreads();
    bf16x8 af[4], bfr[4];
    #pragma unroll
    for (int i = 0; i < 4; ++i)
      af[i] = *(const bf16x8*)(As + (wm + i * 16 + l16) * 32 + quad * 8);
    #pragma unroll
    for (int j = 0; j < 4; ++j)
      bfr[j] = *(const bf16x8*)(Bs + (wn + j * 16 + l16) * 32 + quad * 8);
    #pragma unroll
    for (int i = 0; i < 4; ++i)
      #pragma unroll
      for (int j = 0; j < 4; ++j)
        acc[i][j] = __builtin_amdgcn_mfma_f32_16x16x32_bf16(af[i], bfr[j], acc[i][j], 0, 0, 0);
    __syncthreads();
  }

  #pragma unroll
  for (int i = 0; i < 4; ++i) {
    #pragma unroll
    for (int r = 0; r < 4; ++r) {
      const int row = m0 + wm + i * 16 + quad * 4 + r;
      if (row < cn) {
        const int tok = idx[row];
        #pragma unroll
        for (int j = 0; j < 4; ++j) {
          const int col = n0 + wn + j * 16 + l16;
          const size_t oidx = (size_t)tok * N + col;
          C[oidx] = resf[oidx] + acc[i][j][r];
        }
      }
    }
  }
}

// ---------------- launcher --------------------------------------------
extern "C" void kernel_launch(void* const* d_in, const int* in_sizes, int n_in,
                              void* d_out, int out_size, void* d_ws, size_t ws_size,
                              hipStream_t stream) {
  (void)in_sizes; (void)n_in; (void)out_size; (void)ws_size;
  const float* hidden = (const float*)d_in[0];
  const float* ln1w   = (const float*)d_in[1];
  const float* wq     = (const float*)d_in[2];
  const float* bq     = (const float*)d_in[3];
  const float* wk     = (const float*)d_in[4];
  const float* bk     = (const float*)d_in[5];
  const float* wv     = (const float*)d_in[6];
  const float* bv     = (const float*)d_in[7];
  const float* wo     = (const float*)d_in[8];
  const float* ln2w   = (const float*)d_in[9];
  const float* e1g    = (const float*)d_in[10];
  const float* e1u    = (const float*)d_in[11];
  const float* e1d    = (const float*)d_in[12];
  const float* e2g    = (const float*)d_in[13];
  const float* e2u    = (const float*)d_in[14];
  const float* e2d    = (const float*)d_in[15];
  const float* rw     = (const float*)d_in[16];
  const float* rb     = (const float*)d_in[17];
  float* out = (float*)d_out;
  char* ws = (char*)d_ws;

  const size_t MB = 1024 * 1024;
  // layout (MiB):
  // [0,16)    h1b bf16
  // [16,48)   Qb f32            -> res2 f32 after attention
  // [48,80)   Kb f32            -> h2b bf16 [48,64) after attn
  // [80,96)   Qbf bf16          -> act bf16 [80,123) after attn
  // [96,112)  Kbf bf16              (same act region)
  // [112,128) VT bf16 [b][h][d][s]  (same act region; dead after attn)
  // [128,144) ctxb bf16         -> idx/cnt (dead after wo gemm; zeroed AFTER it)
  // [144,152) wlin bf16 (DxD, reused 4x) -> wbf bf16 [144,166) (MoE, reused 6x)
  u16*   h1b  = (u16*)(ws);
  float* Qb   = (float*)(ws + 16 * MB);
  float* Kb   = (float*)(ws + 48 * MB);
  u16*   Qbf  = (u16*)(ws + 80 * MB);
  u16*   Kbf  = (u16*)(ws + 96 * MB);
  u16*   VT   = (u16*)(ws + 112 * MB);
  u16*   ctxb = (u16*)(ws + 128 * MB);
  float* res2 = Qb;
  u16*   h2b  = (u16*)(ws + 48 * MB);
  int*   idx  = (int*)(ws + 128 * MB);         // 2 x 4096 ints (ctxb region, dead)
  int*   cnt  = (int*)(ws + 128 * MB + 64 * 1024);
  u16*   act  = (u16*)(ws + 80 * MB);
  u16*   wlin = (u16*)(ws + 144 * MB);
  u16*   wbf  = (u16*)(ws + 144 * MB);

  k_rmsnorm1<<<MTOK, 256, 0, stream>>>(hidden, ln1w, h1b);

  const int WD = (D_ * D_) / 8 / 256;      // 2048 blocks per D x D weight
  const int WCONV = (F_ * D_) / 8 / 256;   // 5504 blocks per F x D weight
  dim3 gQKV(D_ / 128, MTOK / 128);

  k_f2bf<<<WD, 256, 0, stream>>>(wq, wlin);
  k_lin_bf16<0><<<gQKV, 256, 0, stream>>>(h1b, wlin, bq, nullptr, Qb, D_, D_);
  k_f2bf<<<WD, 256, 0, stream>>>(wk, wlin);
  k_lin_bf16<0><<<gQKV, 256, 0, stream>>>(h1b, wlin, bk, nullptr, Kb, D_, D_);
  k_f2bf<<<WD, 256, 0, stream>>>(wv, wlin);
  k_lin_bf16<3><<<gQKV, 256, 0, stream>>>(h1b, wlin, bv, nullptr, VT, D_, D_);

  k_rope_bf<<<MTOK, 256, 0, stream>>>(Qb, Kb, Qbf, Kbf);
  k_attn_mfma<<<dim3(32, NH_, 2), 256, 0, stream>>>(Qbf, Kbf, VT, ctxb);

  k_f2bf<<<WD, 256, 0, stream>>>(wo, wlin);
  k_lin_bf16<1><<<gQKV, 256, 0, stream>>>(ctxb, wlin, nullptr, hidden, res2, D_, D_);

  // ctxb region is dead from here; init routing state in it, then route
  k_moe_init<<<1, 256, 0, stream>>>(cnt, idx);
  k_rmsnorm2_router<<<MTOK, 256, 0, stream>>>(res2, ln2w, rw, rb, h2b, cnt, idx);

  dim3 gFU(F_ / 128, MTOK / 128), gDN(D_ / 128, MTOK / 128);

  // expert 1 (tokens with choice==0), routed
  k_f2bf<<<WCONV, 256, 0, stream>>>(e1g, wbf);
  k_moe_gup<0><<<gFU, 256, 0, stream>>>(h2b, wbf, nullptr, idx, cnt, act, F_, D_);
  k_f2bf<<<WCONV, 256, 0, stream>>>(e1u, wbf);
  k_moe_gup<1><<<gFU, 256, 0, stream>>>(h2b, wbf, act, idx, cnt, act, F_, D_);
  k_f2bf<<<WCONV, 256, 0, stream>>>(e1d, wbf);
  k_moe_down<<<gDN, 256, 0, stream>>>(act, wbf, res2, idx, cnt, out, D_, F_);
  // expert 2 (tokens with choice==1), routed
  k_f2bf<<<WCONV, 256, 0, stream>>>(e2g, wbf);
  k_moe_gup<0><<<gFU, 256, 0, stream>>>(h2b, wbf, nullptr, idx + MTOK, cnt + 1, act, F_, D_);
  k_f2bf<<<WCONV, 256, 0, stream>>>(e2u, wbf);
  k_moe_gup<1><<<gFU, 256, 0, stream>>>(h2b, wbf, act, idx + MTOK, cnt + 1, act, F_, D_);
  k_f2bf<<<WCONV, 256, 0, stream>>>(e2d, wbf);
  k_moe_down<<<gDN, 256, 0, stream>>>(act, wbf, res2, idx + MTOK, cnt + 1, out, D_, F_);
}